// Round 11
// baseline (246.142 us; speedup 1.0000x reference)
//
#include <hip/hip_runtime.h>
#include <cstdint>

#define U_NUM 50000
#define F_NUM 20000
#define N_NUM 70000
#define D_EMB 128
#define THRESH 0.3f

typedef _Float16 half8 __attribute__((ext_vector_type(8)));
typedef float f32x4 __attribute__((ext_vector_type(4)));
typedef unsigned short u16x8 __attribute__((ext_vector_type(8)));

// ============ pre-split weights (2 fp16 planes, transposed [n][k]) + zero counters ============
__global__ void presplit_zero(const float* __restrict__ Wu, const float* __restrict__ Wf,
                              const float* __restrict__ Wq, const float* __restrict__ Wk,
                              unsigned short* __restrict__ dst,
                              int* __restrict__ cnt, int* __restrict__ cursor)
{
    int i = blockIdx.x * 256 + threadIdx.x;
    if (i < N_NUM) { cnt[i] = 0; cursor[i] = 0; }
    if (i >= 98304) return;
    float a; size_t d; int pstride;
    if (i < 32768) {
        int n = i >> 8, k = i & 255;
        a = Wu[k * 128 + n]; d = (size_t)n * 256 + k; pstride = 32768;
    } else if (i < 65536) {
        int j = i - 32768; int n = j >> 8, k = j & 255;
        a = Wf[k * 128 + n]; d = 65536 + (size_t)n * 256 + k; pstride = 32768;
    } else if (i < 81920) {
        int j = i - 65536; int n = j >> 7, k = j & 127;
        a = Wq[k * 128 + n]; d = 131072 + (size_t)n * 128 + k; pstride = 16384;
    } else {
        int j = i - 81920; int n = j >> 7, k = j & 127;
        a = Wk[k * 128 + n]; d = 163840 + (size_t)n * 128 + k; pstride = 16384;
    }
    _Float16 c1 = (_Float16)a;            // RNE
    float r = a - (float)c1;
    _Float16 c2 = (_Float16)r;            // RNE
    dst[d]           = __builtin_bit_cast(unsigned short, c1);
    dst[d + pstride] = __builtin_bit_cast(unsigned short, c2);
}

// ============ split 8 f32 -> hi/lo fp16 fragments (RNE scalar casts) ============
__device__ __forceinline__ void split2(const float4 x0, const float4 x1,
                                       half8& h, half8& lo)
{
    float v[8] = {x0.x, x0.y, x0.z, x0.w, x1.x, x1.y, x1.z, x1.w};
#pragma unroll
    for (int i = 0; i < 8; i++) {
        _Float16 c1 = (_Float16)v[i];
        h[i] = c1;
        lo[i] = (_Float16)(v[i] - (float)c1);
    }
}

// ============ GEMM 1: E = relu(feat @ W1 + b1) -> fp16 hi/lo planes ============
// 64 rows x 128 cols per block (A read ONCE); wave = 16 rows x 128 cols.
// No LDS, no barriers: all 8 A chunks prefetched to registers up front; W
// fragments read from global (per-kc 16KB slice is L1/L2-hot, shared by all).
__global__ __launch_bounds__(256)
void gemm1(const float* __restrict__ uf, const float* __restrict__ ff,
           const unsigned short* __restrict__ Wsp,
           const float* __restrict__ bu, const float* __restrict__ bfo,
           unsigned short* __restrict__ Eh, int nbU)
{
    unsigned short* El = Eh + (size_t)N_NUM * 128;
    const int bid = blockIdx.x;
    const bool isU = bid < nbU;
    const int lb  = isU ? bid : bid - nbU;
    const int Mloc = isU ? U_NUM : F_NUM;
    const int combBase = isU ? 0 : U_NUM;
    const float* A  = isU ? uf : ff;
    const float* b1 = isU ? bu : bfo;
    const unsigned short* W = Wsp + (isU ? 0 : 65536);

    const int tid = threadIdx.x;
    const int w  = tid >> 6;
    const int l  = tid & 63;
    const int lm = l & 15;
    const int lq = l >> 4;

    const int rowBase = lb * 64 + w * 16;
    const int r = min(rowBase + lm, Mloc - 1);
    const float* arow = A + (size_t)r * 256 + lq * 8;

    // ---- load ALL A chunks up front (64 VGPR, 16 KB in flight per wave) ----
    float4 a0[8], a1v[8];
#pragma unroll
    for (int kc = 0; kc < 8; ++kc) {
        const float4* p4 = (const float4*)(arow + kc * 32);
        a0[kc] = p4[0]; a1v[kc] = p4[1];
    }

    f32x4 acc[8];
#pragma unroll
    for (int j = 0; j < 8; j++) acc[j] = (f32x4)0.f;

#pragma unroll
    for (int kc = 0; kc < 8; ++kc) {
        half8 ah, al;
        split2(a0[kc], a1v[kc], ah, al);
#pragma unroll
        for (int cb = 0; cb < 8; ++cb) {
            const unsigned short* bp = W + (size_t)(cb * 16 + lm) * 256 + kc * 32 + lq * 8;
            half8 bh = *(const half8*)bp;
            half8 bl = *(const half8*)(bp + 32768);
            acc[cb] = __builtin_amdgcn_mfma_f32_16x16x32_f16(al, bh, acc[cb], 0, 0, 0);
            acc[cb] = __builtin_amdgcn_mfma_f32_16x16x32_f16(ah, bl, acc[cb], 0, 0, 0);
            acc[cb] = __builtin_amdgcn_mfma_f32_16x16x32_f16(ah, bh, acc[cb], 0, 0, 0);
        }
    }

    // ---- epilogue: e = relu(acc + b); store fp16 hi/lo planes (== split2(e)) ----
#pragma unroll
    for (int cb = 0; cb < 8; ++cb) {
        const int col = cb * 16 + lm;
        const float bb = b1[col];
#pragma unroll
        for (int rg = 0; rg < 4; ++rg) {
            int lr = rowBase + lq * 4 + rg;
            if (lr < Mloc) {
                size_t rr = (size_t)(combBase + lr);
                float e = fmaxf(acc[cb][rg] + bb, 0.f);
                _Float16 c1 = (_Float16)e;
                _Float16 c2 = (_Float16)(e - (float)c1);
                Eh[rr * 128 + col] = __builtin_bit_cast(unsigned short, c1);
                El[rr * 128 + col] = __builtin_bit_cast(unsigned short, c2);
            }
        }
    }
}

// ============ GEMM 2: QK = E @ W2 (f32 + fp16 copy); same no-LDS structure ============
__global__ __launch_bounds__(256)
void gemm2(const unsigned short* __restrict__ Eh,
           const unsigned short* __restrict__ Wsp,
           float* __restrict__ Qo, unsigned short* __restrict__ QKh, int nbU)
{
    const unsigned short* El = Eh + (size_t)N_NUM * 128;
    const int bid = blockIdx.x;
    const bool isU = bid < nbU;
    const int lb  = isU ? bid : bid - nbU;
    const int Mloc = isU ? U_NUM : F_NUM;
    const int combBase = isU ? 0 : U_NUM;
    const unsigned short* W = Wsp + (isU ? 131072 : 163840);

    const int tid = threadIdx.x;
    const int w  = tid >> 6;
    const int l  = tid & 63;
    const int lm = l & 15;
    const int lq = l >> 4;

    const int rowBase = lb * 64 + w * 16;
    const int r = min(rowBase + lm, Mloc - 1) + combBase;
    const size_t erow = (size_t)r * 128 + lq * 8;

    // ---- load ALL E chunks up front (hi+lo planes, 32 VGPR) ----
    u16x8 ph[4], pl[4];
#pragma unroll
    for (int kc = 0; kc < 4; ++kc) {
        ph[kc] = *(const u16x8*)(Eh + erow + kc * 32);
        pl[kc] = *(const u16x8*)(El + erow + kc * 32);
    }

    f32x4 acc[8];
#pragma unroll
    for (int j = 0; j < 8; j++) acc[j] = (f32x4)0.f;

#pragma unroll
    for (int kc = 0; kc < 4; ++kc) {
        half8 ah = __builtin_bit_cast(half8, ph[kc]);
        half8 al = __builtin_bit_cast(half8, pl[kc]);
#pragma unroll
        for (int cb = 0; cb < 8; ++cb) {
            const unsigned short* bp = W + (size_t)(cb * 16 + lm) * 128 + kc * 32 + lq * 8;
            half8 bh = *(const half8*)bp;
            half8 bl = *(const half8*)(bp + 16384);
            acc[cb] = __builtin_amdgcn_mfma_f32_16x16x32_f16(al, bh, acc[cb], 0, 0, 0);
            acc[cb] = __builtin_amdgcn_mfma_f32_16x16x32_f16(ah, bl, acc[cb], 0, 0, 0);
            acc[cb] = __builtin_amdgcn_mfma_f32_16x16x32_f16(ah, bh, acc[cb], 0, 0, 0);
        }
    }

#pragma unroll
    for (int cb = 0; cb < 8; ++cb) {
        const int col = cb * 16 + lm;
#pragma unroll
        for (int rg = 0; rg < 4; ++rg) {
            int lr = rowBase + lq * 4 + rg;
            if (lr < Mloc) {
                size_t rr = (size_t)(combBase + lr);
                float v = acc[cb][rg];
                Qo[rr * 128 + col] = v;
                QKh[rr * 128 + col] = __builtin_bit_cast(unsigned short, (_Float16)v);
            }
        }
    }
}

// ============ per-edge multi-head cosine mask: fp16 gather + f32 borderline recheck ============
__global__ __launch_bounds__(256)
void edge_kernel(const int* __restrict__ ei, int Edir,
                 const unsigned short* __restrict__ QKh, const float* __restrict__ QKf,
                 const float* __restrict__ cwts,
                 float* __restrict__ maskf, int* __restrict__ cnt, int Eund)
{
    int gid = blockIdx.x * 256 + threadIdx.x;
    int e = gid >> 3;
    if (e >= Eund) return;
    int sub = gid & 7;
    int row = ei[e];
    int col = ei[Edir + e];
    row = min(max(row, 0), N_NUM - 1);
    col = min(max(col, 0), N_NUM - 1);
    int u  = (row < U_NUM) ? row : col;
    int fg = (row < U_NUM) ? col : row;
    u = min(max(u, 0), U_NUM - 1);
    int f = min(max(fg - U_NUM, 0), F_NUM - 1);
    const size_t qrow = (size_t)u * D_EMB;
    const size_t krow = (size_t)(U_NUM + f) * D_EMB;

    const unsigned short* qh = QKh + qrow + sub * 16;
    const unsigned short* kh = QKh + krow + sub * 16;
    u16x8 qa = *(const u16x8*)(qh);
    u16x8 qb = *(const u16x8*)(qh + 8);
    u16x8 ka = *(const u16x8*)(kh);
    u16x8 kb = *(const u16x8*)(kh + 8);
    float dot = 0.f, qq = 0.f, kk = 0.f;
#pragma unroll
    for (int i = 0; i < 8; i++) {
        float qv = (float)__builtin_bit_cast(_Float16, (unsigned short)qa[i]);
        float kv = (float)__builtin_bit_cast(_Float16, (unsigned short)ka[i]);
        dot += qv * kv; qq += qv * qv; kk += kv * kv;
    }
#pragma unroll
    for (int i = 0; i < 8; i++) {
        float qv = (float)__builtin_bit_cast(_Float16, (unsigned short)qb[i]);
        float kv = (float)__builtin_bit_cast(_Float16, (unsigned short)kb[i]);
        dot += qv * kv; qq += qv * qv; kk += kv * kv;
    }
    dot += __shfl_xor(dot, 1);
    qq  += __shfl_xor(qq, 1);
    kk  += __shfl_xor(kk, 1);
    float denom = sqrtf(qq) * sqrtf(kk) + 1e-8f;
    float sim = dot / denom;
    float s = sim + __shfl_xor(sim, 2);
    s += __shfl_xor(s, 4);
    float mean = s * 0.25f;

    if (fabsf(mean - THRESH) < 0.03f) {
        const float4* qp = (const float4*)(QKf + qrow + sub * 16);
        const float4* kp = (const float4*)(QKf + krow + sub * 16);
        float dot2 = 0.f, qq2 = 0.f, kk2 = 0.f;
#pragma unroll
        for (int i = 0; i < 4; i++) {
            float4 a = qp[i]; float4 b = kp[i];
            dot2 += a.x * b.x + a.y * b.y + a.z * b.z + a.w * b.w;
            qq2  += a.x * a.x + a.y * a.y + a.z * a.z + a.w * a.w;
            kk2  += b.x * b.x + b.y * b.y + b.z * b.z + b.w * b.w;
        }
        dot2 += __shfl_xor(dot2, 1);
        qq2  += __shfl_xor(qq2, 1);
        kk2  += __shfl_xor(kk2, 1);
        float denom2 = sqrtf(qq2) * sqrtf(kk2) + 1e-8f;
        float sim2 = dot2 / denom2;
        float s2 = sim2 + __shfl_xor(sim2, 2);
        s2 += __shfl_xor(s2, 4);
        mean = s2 * 0.25f;
    }

    float mf = (mean > THRESH) ? 1.f : 0.f;
    float cw0 = cwts[0], cw1 = cwts[1];
    float mx = fmaxf(cw0, cw1);
    float e0 = expf(cw0 - mx), e1 = expf(cw1 - mx);
    float inv = 1.f / (e0 + e1);
    float fused = e0 * inv + (e1 * inv) * mf;
    float em = (fused > 0.5f) ? 1.f : 0.f;

    if (sub == 0) {
        maskf[e] = em;
        if (em != 0.f) {
            atomicAdd(&cnt[row], 1);
            atomicAdd(&cnt[col], 1);
        }
    }
}

// ============ exclusive scan over cnt[N] (3 kernels) ============
__global__ void scan_part(const int* __restrict__ cnt, int* __restrict__ part, int n)
{
    __shared__ int sd[256];
    int b = blockIdx.x, t = threadIdx.x;
    int base = b * 1024;
    int s = 0;
#pragma unroll
    for (int j = 0; j < 4; j++) {
        int idx = base + t + j * 256;
        if (idx < n) s += cnt[idx];
    }
    sd[t] = s; __syncthreads();
    for (int d = 128; d > 0; d >>= 1) {
        if (t < d) sd[t] += sd[t + d];
        __syncthreads();
    }
    if (t == 0) part[b] = sd[0];
}

__global__ void scan_small(int* part, int nb)
{
    __shared__ int sd[256];
    int t = threadIdx.x;
    sd[t] = (t < nb) ? part[t] : 0;
    __syncthreads();
    for (int d = 1; d < 256; d <<= 1) {
        int x = (t >= d) ? sd[t - d] : 0;
        __syncthreads();
        sd[t] += x;
        __syncthreads();
    }
    if (t < nb) part[t] = (t > 0) ? sd[t - 1] : 0;
}

__global__ void scan_final(const int* __restrict__ cnt, const int* __restrict__ part,
                           int* __restrict__ offs, int n)
{
    __shared__ int sd[256];
    int b = blockIdx.x, t = threadIdx.x;
    int base = b * 1024 + t * 4;
    int v[4]; int s = 0;
#pragma unroll
    for (int j = 0; j < 4; j++) {
        int idx = base + j;
        v[j] = (idx < n) ? cnt[idx] : 0;
        s += v[j];
    }
    sd[t] = s; __syncthreads();
    for (int d = 1; d < 256; d <<= 1) {
        int x = (t >= d) ? sd[t - d] : 0;
        __syncthreads();
        sd[t] += x;
        __syncthreads();
    }
    int prefix = part[b] + ((t > 0) ? sd[t - 1] : 0);
#pragma unroll
    for (int j = 0; j < 4; j++) {
        int idx = base + j;
        if (idx < n) offs[idx] = prefix;
        prefix += v[j];
    }
}

// ============ CSR scatter ============
__global__ void scatter_kernel(const int* __restrict__ ei, int Edir,
                               const float* __restrict__ maskf,
                               const int* __restrict__ cnt, const int* __restrict__ offs,
                               int* __restrict__ cursor,
                               int* __restrict__ cnbr, float* __restrict__ cwA, int Eund)
{
    int e = blockIdx.x * 256 + threadIdx.x;
    if (e >= Eund) return;
    if (maskf[e] == 0.f) return;
    int row = ei[e], col = ei[Edir + e];
    row = min(max(row, 0), N_NUM - 1);
    col = min(max(col, 0), N_NUM - 1);
    float w = 1.0f / sqrtf((float)cnt[row] * (float)cnt[col]);
    int p1 = offs[row] + atomicAdd(&cursor[row], 1);
    cnbr[p1] = col; cwA[p1] = w;
    int p2 = offs[col] + atomicAdd(&cursor[col], 1);
    cnbr[p2] = row; cwA[p2] = w;
}

// ============ propagation ============
template<int MODE>
__global__ __launch_bounds__(256)
void prop(const int* __restrict__ offs, const int* __restrict__ cnt,
          const int* __restrict__ cnbr, const float* __restrict__ cwA,
          const float* __restrict__ xin,
          const float* __restrict__ ue, const float* __restrict__ ie,
          const float* __restrict__ x1b, float* __restrict__ xout,
          float* __restrict__ tail)
{
    int wid = (blockIdx.x << 2) + (threadIdx.x >> 6);
    if (wid >= N_NUM) return;
    int lane = threadIdx.x & 63;
    int num = cnt[wid];
    if (MODE != 2 && num == 0) return;
    int start = (num > 0) ? offs[wid] : 0;
    float ax = 0.f, ay = 0.f;

    auto srcp = [&](int c) -> const float* {
        if (MODE == 0)
            return (c < U_NUM) ? (ue + (size_t)c * D_EMB) : (ie + (size_t)(c - U_NUM) * D_EMB);
        else
            return xin + (size_t)c * D_EMB;
    };

    int j = 0;
    for (; j + 4 <= num; j += 4) {
        int c0i = cnbr[start + j],     c1i = cnbr[start + j + 1];
        int c2i = cnbr[start + j + 2], c3i = cnbr[start + j + 3];
        float w0 = cwA[start + j],     w1 = cwA[start + j + 1];
        float w2 = cwA[start + j + 2], w3 = cwA[start + j + 3];
        float2 v0 = *(const float2*)(srcp(c0i) + lane * 2);
        float2 v1 = *(const float2*)(srcp(c1i) + lane * 2);
        float2 v2 = *(const float2*)(srcp(c2i) + lane * 2);
        float2 v3 = *(const float2*)(srcp(c3i) + lane * 2);
        ax += w0 * v0.x; ay += w0 * v0.y;
        ax += w1 * v1.x; ay += w1 * v1.y;
        ax += w2 * v2.x; ay += w2 * v2.y;
        ax += w3 * v3.x; ay += w3 * v3.y;
    }
    for (; j < num; ++j) {
        int c = cnbr[start + j]; float w = cwA[start + j];
        float2 v = *(const float2*)(srcp(c) + lane * 2);
        ax += w * v.x; ay += w * v.y;
    }

    size_t o = (size_t)wid * D_EMB + lane * 2;
    if (MODE == 2) {
        const float* x0p = (wid < U_NUM) ? (ue + (size_t)wid * D_EMB)
                                         : (ie + (size_t)(wid - U_NUM) * D_EMB);
        float2 x0v = *(const float2*)(x0p + lane * 2);
        *(float2*)(tail + o) = x0v;                     // embed copy (output tail)
        float ox, oy;
        if (num == 0) {
            ox = x0v.x * 0.25f; oy = x0v.y * 0.25f;
        } else {
            float2 x1v = *(const float2*)(x1b + o);
            float2 x2v = *(const float2*)(xin + o);
            ox = ((x0v.x + x1v.x) + x2v.x + ax) * 0.25f;
            oy = ((x0v.y + x1v.y) + x2v.y + ay) * 0.25f;
        }
        *(float2*)(xout + o) = make_float2(ox, oy);
    } else {
        *(float2*)(xout + o) = make_float2(ax, ay);
    }
}

// ============ launcher ============
extern "C" void kernel_launch(void* const* d_in, const int* in_sizes, int n_in,
                              void* d_out, int out_size, void* d_ws, size_t ws_size,
                              hipStream_t stream)
{
    const float* user_feat  = (const float*)d_in[0];
    const float* food_feat  = (const float*)d_in[1];
    const int*   ei         = (const int*)d_in[2];
    const float* W_user     = (const float*)d_in[3];
    const float* b_user     = (const float*)d_in[4];
    const float* W_food     = (const float*)d_in[5];
    const float* b_food     = (const float*)d_in[6];
    const float* Wq         = (const float*)d_in[7];
    const float* Wk         = (const float*)d_in[8];
    const float* cwts       = (const float*)d_in[9];
    const float* user_embed = (const float*)d_in[10];
    const float* item_embed = (const float*)d_in[11];

    const int Edir = in_sizes[2] / 2;   // 1.2M directed edges
    const int Eund = Edir / 2;          // 600K undirected ([u,f] || [f,u])

    char* ws = (char*)d_ws;
    size_t off = 0;
    auto alloc = [&](size_t nb) { size_t o = off; off += (nb + 255) & ~(size_t)255; return o; };

    float* Q     = (float*)(ws + alloc((size_t)N_NUM * D_EMB * 4));  // f32 Q|K -> xA
    float* xB    = (float*)(ws + alloc((size_t)N_NUM * D_EMB * 4));  // Eh|El planes, later prop scratch
    unsigned short* QKh = (unsigned short*)(ws + alloc((size_t)N_NUM * D_EMB * 2));
    float* maskf = (float*)(ws + alloc((size_t)Eund * 4));
    int*   cnt   = (int*)  (ws + alloc((size_t)N_NUM * 4));
    int*   offs  = (int*)  (ws + alloc((size_t)N_NUM * 4));
    int*   cursor= (int*)  (ws + alloc((size_t)N_NUM * 4));
    int*   cnbr  = (int*)  (ws + alloc((size_t)Edir * 4));
    float* cwA   = (float*)(ws + alloc((size_t)Edir * 4));
    int*   part  = (int*)  (ws + alloc((size_t)256 * 4));
    unsigned short* Wsp = (unsigned short*)(ws + alloc((size_t)196608 * 2));
    (void)ws_size; (void)n_in; (void)out_size;

    float* xA = Q;                              // N x 128, reuses Q|K after the edge stage
    unsigned short* Ehl = (unsigned short*)xB;  // 2 fp16 planes, dead before prop<0>

    // 1) pre-split weights + zero counters
    presplit_zero<<<384, 256, 0, stream>>>(W_user, W_food, Wq, Wk, Wsp, cnt, cursor);

    // 2) two GEMMs: 64-row full-width blocks, no LDS, no barriers
    const int nbU = (U_NUM + 63) / 64;   // 782
    const int nbF = (F_NUM + 63) / 64;   // 313
    gemm1<<<nbU + nbF, 256, 0, stream>>>(user_feat, food_feat, Wsp, b_user, b_food,
                                         Ehl, nbU);
    gemm2<<<nbU + nbF, 256, 0, stream>>>(Ehl, Wsp, Q, QKh, nbU);

    // 3) per-edge mask + degree counts (fp16 gather, f32 borderline recheck)
    edge_kernel<<<(Eund * 8 + 255) / 256, 256, 0, stream>>>(ei, Edir, QKh, Q, cwts,
                                                            maskf, cnt, Eund);

    // 4) exclusive scan of cnt -> offs
    int nb = (N_NUM + 1023) / 1024;
    scan_part <<<nb, 256, 0, stream>>>(cnt, part, N_NUM);
    scan_small<<<1, 256, 0, stream>>>(part, nb);
    scan_final<<<nb, 256, 0, stream>>>(cnt, part, offs, N_NUM);

    // 5) CSR scatter
    scatter_kernel<<<(Eund + 255) / 256, 256, 0, stream>>>(ei, Edir, maskf, cnt, offs,
                                                           cursor, cnbr, cwA, Eund);

    // 6) three LightGCN layers; last fuses epilogue + embeds tail copy
    int pb = (N_NUM + 3) / 4;
    float* tail = (float*)d_out + (size_t)N_NUM * D_EMB;
    prop<0><<<pb, 256, 0, stream>>>(offs, cnt, cnbr, cwA, nullptr, user_embed, item_embed,
                                    nullptr, xB, nullptr);
    prop<1><<<pb, 256, 0, stream>>>(offs, cnt, cnbr, cwA, xB, user_embed, item_embed,
                                    nullptr, xA, nullptr);
    prop<2><<<pb, 256, 0, stream>>>(offs, cnt, cnbr, cwA, xA, user_embed, item_embed,
                                    xB, (float*)d_out, tail);
}

// Round 12
// 166.379 us; speedup vs baseline: 1.4794x; 1.4794x over previous
//
#include <hip/hip_runtime.h>
#include <cstdint>

#define U_NUM 50000
#define F_NUM 20000
#define N_NUM 70000
#define D_EMB 128
#define THRESH 0.3f

typedef _Float16 half8 __attribute__((ext_vector_type(8)));
typedef float f32x4 __attribute__((ext_vector_type(4)));
typedef unsigned short u16x8 __attribute__((ext_vector_type(8)));

// ============ pre-split weights (2 fp16 planes, transposed [n][k]) + zero counters ============
__global__ void presplit_zero(const float* __restrict__ Wu, const float* __restrict__ Wf,
                              const float* __restrict__ Wq, const float* __restrict__ Wk,
                              unsigned short* __restrict__ dst,
                              int* __restrict__ cnt, int* __restrict__ cursor)
{
    int i = blockIdx.x * 256 + threadIdx.x;
    if (i < N_NUM) { cnt[i] = 0; cursor[i] = 0; }
    if (i >= 98304) return;
    float a; size_t d; int pstride;
    if (i < 32768) {
        int n = i >> 8, k = i & 255;
        a = Wu[k * 128 + n]; d = (size_t)n * 256 + k; pstride = 32768;
    } else if (i < 65536) {
        int j = i - 32768; int n = j >> 8, k = j & 255;
        a = Wf[k * 128 + n]; d = 65536 + (size_t)n * 256 + k; pstride = 32768;
    } else if (i < 81920) {
        int j = i - 65536; int n = j >> 7, k = j & 127;
        a = Wq[k * 128 + n]; d = 131072 + (size_t)n * 128 + k; pstride = 16384;
    } else {
        int j = i - 81920; int n = j >> 7, k = j & 127;
        a = Wk[k * 128 + n]; d = 163840 + (size_t)n * 128 + k; pstride = 16384;
    }
    _Float16 c1 = (_Float16)a;            // RNE
    float r = a - (float)c1;
    _Float16 c2 = (_Float16)r;            // RNE
    dst[d]           = __builtin_bit_cast(unsigned short, c1);
    dst[d + pstride] = __builtin_bit_cast(unsigned short, c2);
}

// ============ split 8 f32 -> hi/lo fp16 fragments (RNE scalar casts) ============
__device__ __forceinline__ void split2v(const f32x4 x0, const f32x4 x1,
                                        half8& h, half8& lo)
{
    float v[8] = {x0[0], x0[1], x0[2], x0[3], x1[0], x1[1], x1[2], x1[3]};
#pragma unroll
    for (int i = 0; i < 8; i++) {
        _Float16 c1 = (_Float16)v[i];
        h[i] = c1;
        lo[i] = (_Float16)(v[i] - (float)c1);
    }
}

// ============ GEMM 1: E = relu(feat @ W1 + b1) -> fp16 hi/lo planes ============
// v7 structure (128r x 64c block, LDS-dbuf W, per-kc barrier) + ALL A chunks
// loaded up front (128 VGPR): first barrier drains one BW-bound burst, k-loop
// then only touches LDS/L2.
__global__ __launch_bounds__(256, 2)
void gemm1(const float* __restrict__ uf, const float* __restrict__ ff,
           const unsigned short* __restrict__ Wsp,
           const float* __restrict__ bu, const float* __restrict__ bfo,
           unsigned short* __restrict__ Eh, int nbU2)
{
    __shared__ unsigned short Bs[2][2][64][40];   // 20480 B

    unsigned short* El = Eh + (size_t)N_NUM * 128;
    const int bid = blockIdx.x;
    const bool isU = bid < nbU2;
    const int lb  = isU ? bid : bid - nbU2;
    const int rowTile = lb >> 1;
    const int n0 = (lb & 1) * 64;
    const int Mloc = isU ? U_NUM : F_NUM;
    const int combBase = isU ? 0 : U_NUM;
    const float* A  = isU ? uf : ff;
    const float* b1 = isU ? bu : bfo;
    const unsigned short* W = Wsp + (isU ? 0 : 65536);
    const int Wp = 32768;

    const int tid = threadIdx.x;
    const int w  = tid >> 6;
    const int l  = tid & 63;
    const int lm = l & 15;
    const int lq = l >> 4;
    const int wr = w * 32;

    const int sp = tid >> 7;
    const int sn = (tid >> 1) & 63;
    const int sh = tid & 1;
    const unsigned short* wsrc = W + (size_t)sp * Wp + (size_t)(n0 + sn) * 256 + sh * 16;

    auto stage = [&](int buf, int kc) {
        const unsigned short* s = wsrc + kc * 32;
        uint4 v0 = *(const uint4*)(s);
        uint4 v1 = *(const uint4*)(s + 8);
        *(uint4*)&Bs[buf][sp][sn][sh * 16]     = v0;
        *(uint4*)&Bs[buf][sp][sn][sh * 16 + 8] = v1;
    };

    const float* arow[2];
#pragma unroll
    for (int rb = 0; rb < 2; ++rb) {
        int r = min(rowTile * 128 + wr + rb * 16 + lm, Mloc - 1);
        arow[rb] = A + (size_t)r * 256 + lq * 8;
    }

    // ---- load ALL A chunks up front (2rb x 8kc x 2 float4 = 128 VGPR) ----
    f32x4 a0[2][8], a1r[2][8];
#pragma unroll
    for (int rb = 0; rb < 2; ++rb)
#pragma unroll
        for (int kc = 0; kc < 8; ++kc) {
            const f32x4* p4 = (const f32x4*)(arow[rb] + kc * 32);
            a0[rb][kc] = p4[0]; a1r[rb][kc] = p4[1];
        }

    stage(0, 0);
    // pin the A loads above the first barrier (keep-alive consumption)
#pragma unroll
    for (int rb = 0; rb < 2; ++rb)
#pragma unroll
        for (int kc = 0; kc < 8; ++kc)
            asm volatile("" :: "v"(a0[rb][kc][0]), "v"(a1r[rb][kc][0]));
    __syncthreads();

    f32x4 acc[2][4];
#pragma unroll
    for (int i = 0; i < 2; i++)
#pragma unroll
        for (int j = 0; j < 4; j++) acc[i][j] = (f32x4)0.f;

    int buf = 0;
#pragma unroll
    for (int kc = 0; kc < 8; ++kc) {
        if (kc < 7) stage(buf ^ 1, kc + 1);
        half8 ah[2], al[2];
#pragma unroll
        for (int rb = 0; rb < 2; ++rb) split2v(a0[rb][kc], a1r[rb][kc], ah[rb], al[rb]);
#pragma unroll
        for (int cb = 0; cb < 4; ++cb) {
            const unsigned short* bp = &Bs[buf][0][cb * 16 + lm][lq * 8];
            half8 bh = *(const half8*)bp;
            half8 bl = *(const half8*)(bp + 64 * 40);
#pragma unroll
            for (int rb = 0; rb < 2; ++rb) {
                acc[rb][cb] = __builtin_amdgcn_mfma_f32_16x16x32_f16(al[rb], bh, acc[rb][cb], 0, 0, 0);
                acc[rb][cb] = __builtin_amdgcn_mfma_f32_16x16x32_f16(ah[rb], bl, acc[rb][cb], 0, 0, 0);
                acc[rb][cb] = __builtin_amdgcn_mfma_f32_16x16x32_f16(ah[rb], bh, acc[rb][cb], 0, 0, 0);
            }
        }
        __syncthreads();
        buf ^= 1;
    }

    // ---- epilogue: e = relu(acc + b); store fp16 hi/lo planes (== split2(e)) ----
#pragma unroll
    for (int cb = 0; cb < 4; ++cb) {
        const int col = n0 + cb * 16 + lm;
        const float bb = b1[col];
#pragma unroll
        for (int rb = 0; rb < 2; ++rb)
#pragma unroll
            for (int rg = 0; rg < 4; ++rg) {
                int lr = wr + rb * 16 + lq * 4 + rg;
                if (rowTile * 128 + lr < Mloc) {
                    size_t rr = (size_t)(combBase + rowTile * 128 + lr);
                    float e = fmaxf(acc[rb][cb][rg] + bb, 0.f);
                    _Float16 c1 = (_Float16)e;
                    _Float16 c2 = (_Float16)(e - (float)c1);
                    Eh[rr * 128 + col] = __builtin_bit_cast(unsigned short, c1);
                    El[rr * 128 + col] = __builtin_bit_cast(unsigned short, c2);
                }
            }
    }
}

// ============ GEMM 2: QK = E @ W2 (f32 + fp16 copy); E planes upfront ============
__global__ __launch_bounds__(256, 3)
void gemm2(const unsigned short* __restrict__ Eh,
           const unsigned short* __restrict__ Wsp,
           float* __restrict__ Qo, unsigned short* __restrict__ QKh, int nbU2)
{
    __shared__ unsigned short Bs[2][2][64][40];

    const unsigned short* El = Eh + (size_t)N_NUM * 128;
    const int bid = blockIdx.x;
    const bool isU = bid < nbU2;
    const int lb  = isU ? bid : bid - nbU2;
    const int rowTile = lb >> 1;
    const int n0 = (lb & 1) * 64;
    const int Mloc = isU ? U_NUM : F_NUM;
    const int combBase = isU ? 0 : U_NUM;
    const unsigned short* W = Wsp + (isU ? 131072 : 163840);
    const int Wp = 16384;

    const int tid = threadIdx.x;
    const int w  = tid >> 6;
    const int l  = tid & 63;
    const int lm = l & 15;
    const int lq = l >> 4;
    const int wr = w * 32;

    const int sp = tid >> 7;
    const int sn = (tid >> 1) & 63;
    const int sh = tid & 1;
    const unsigned short* wsrc = W + (size_t)sp * Wp + (size_t)(n0 + sn) * 128 + sh * 16;

    auto stage = [&](int buf, int kc) {
        const unsigned short* s = wsrc + kc * 32;
        uint4 v0 = *(const uint4*)(s);
        uint4 v1 = *(const uint4*)(s + 8);
        *(uint4*)&Bs[buf][sp][sn][sh * 16]     = v0;
        *(uint4*)&Bs[buf][sp][sn][sh * 16 + 8] = v1;
    };

    size_t erow[2];
#pragma unroll
    for (int rb = 0; rb < 2; ++rb) {
        int r = min(rowTile * 128 + wr + rb * 16 + lm, Mloc - 1) + combBase;
        erow[rb] = (size_t)r * 128 + lq * 8;
    }

    // ---- load ALL E chunks up front (16 u16x8 = 64 VGPR) ----
    u16x8 ph[2][4], pl[2][4];
#pragma unroll
    for (int rb = 0; rb < 2; ++rb)
#pragma unroll
        for (int kc = 0; kc < 4; ++kc) {
            ph[rb][kc] = *(const u16x8*)(Eh + erow[rb] + kc * 32);
            pl[rb][kc] = *(const u16x8*)(El + erow[rb] + kc * 32);
        }

    stage(0, 0);
#pragma unroll
    for (int rb = 0; rb < 2; ++rb)
#pragma unroll
        for (int kc = 0; kc < 4; ++kc)
            asm volatile("" :: "v"(ph[rb][kc][0]), "v"(pl[rb][kc][0]));
    __syncthreads();

    f32x4 acc[2][4];
#pragma unroll
    for (int i = 0; i < 2; i++)
#pragma unroll
        for (int j = 0; j < 4; j++) acc[i][j] = (f32x4)0.f;

    int buf = 0;
#pragma unroll
    for (int kc = 0; kc < 4; ++kc) {
        if (kc < 3) stage(buf ^ 1, kc + 1);
#pragma unroll
        for (int cb = 0; cb < 4; ++cb) {
            const unsigned short* bp = &Bs[buf][0][cb * 16 + lm][lq * 8];
            half8 bh = *(const half8*)bp;
            half8 bl = *(const half8*)(bp + 64 * 40);
#pragma unroll
            for (int rb = 0; rb < 2; ++rb) {
                half8 ah = __builtin_bit_cast(half8, ph[rb][kc]);
                half8 al = __builtin_bit_cast(half8, pl[rb][kc]);
                acc[rb][cb] = __builtin_amdgcn_mfma_f32_16x16x32_f16(al, bh, acc[rb][cb], 0, 0, 0);
                acc[rb][cb] = __builtin_amdgcn_mfma_f32_16x16x32_f16(ah, bl, acc[rb][cb], 0, 0, 0);
                acc[rb][cb] = __builtin_amdgcn_mfma_f32_16x16x32_f16(ah, bh, acc[rb][cb], 0, 0, 0);
            }
        }
        __syncthreads();
        buf ^= 1;
    }

#pragma unroll
    for (int cb = 0; cb < 4; ++cb) {
        const int col = n0 + cb * 16 + lm;
#pragma unroll
        for (int rb = 0; rb < 2; ++rb)
#pragma unroll
            for (int rg = 0; rg < 4; ++rg) {
                int lr = wr + rb * 16 + lq * 4 + rg;
                if (rowTile * 128 + lr < Mloc) {
                    size_t rr = (size_t)(combBase + rowTile * 128 + lr);
                    float v = acc[rb][cb][rg];
                    Qo[rr * 128 + col] = v;
                    QKh[rr * 128 + col] = __builtin_bit_cast(unsigned short, (_Float16)v);
                }
            }
    }
}

// ============ per-edge multi-head cosine mask: fp16 gather + f32 borderline recheck ============
__global__ __launch_bounds__(256)
void edge_kernel(const int* __restrict__ ei, int Edir,
                 const unsigned short* __restrict__ QKh, const float* __restrict__ QKf,
                 const float* __restrict__ cwts,
                 float* __restrict__ maskf, int* __restrict__ cnt, int Eund)
{
    int gid = blockIdx.x * 256 + threadIdx.x;
    int e = gid >> 3;
    if (e >= Eund) return;
    int sub = gid & 7;
    int row = ei[e];
    int col = ei[Edir + e];
    row = min(max(row, 0), N_NUM - 1);
    col = min(max(col, 0), N_NUM - 1);
    int u  = (row < U_NUM) ? row : col;
    int fg = (row < U_NUM) ? col : row;
    u = min(max(u, 0), U_NUM - 1);
    int f = min(max(fg - U_NUM, 0), F_NUM - 1);
    const size_t qrow = (size_t)u * D_EMB;
    const size_t krow = (size_t)(U_NUM + f) * D_EMB;

    const unsigned short* qh = QKh + qrow + sub * 16;
    const unsigned short* kh = QKh + krow + sub * 16;
    u16x8 qa = *(const u16x8*)(qh);
    u16x8 qb = *(const u16x8*)(qh + 8);
    u16x8 ka = *(const u16x8*)(kh);
    u16x8 kb = *(const u16x8*)(kh + 8);
    float dot = 0.f, qq = 0.f, kk = 0.f;
#pragma unroll
    for (int i = 0; i < 8; i++) {
        float qv = (float)__builtin_bit_cast(_Float16, (unsigned short)qa[i]);
        float kv = (float)__builtin_bit_cast(_Float16, (unsigned short)ka[i]);
        dot += qv * kv; qq += qv * qv; kk += kv * kv;
    }
#pragma unroll
    for (int i = 0; i < 8; i++) {
        float qv = (float)__builtin_bit_cast(_Float16, (unsigned short)qb[i]);
        float kv = (float)__builtin_bit_cast(_Float16, (unsigned short)kb[i]);
        dot += qv * kv; qq += qv * qv; kk += kv * kv;
    }
    dot += __shfl_xor(dot, 1);
    qq  += __shfl_xor(qq, 1);
    kk  += __shfl_xor(kk, 1);
    float denom = sqrtf(qq) * sqrtf(kk) + 1e-8f;
    float sim = dot / denom;
    float s = sim + __shfl_xor(sim, 2);
    s += __shfl_xor(s, 4);
    float mean = s * 0.25f;

    if (fabsf(mean - THRESH) < 0.03f) {
        const float4* qp = (const float4*)(QKf + qrow + sub * 16);
        const float4* kp = (const float4*)(QKf + krow + sub * 16);
        float dot2 = 0.f, qq2 = 0.f, kk2 = 0.f;
#pragma unroll
        for (int i = 0; i < 4; i++) {
            float4 a = qp[i]; float4 b = kp[i];
            dot2 += a.x * b.x + a.y * b.y + a.z * b.z + a.w * b.w;
            qq2  += a.x * a.x + a.y * a.y + a.z * a.z + a.w * a.w;
            kk2  += b.x * b.x + b.y * b.y + b.z * b.z + b.w * b.w;
        }
        dot2 += __shfl_xor(dot2, 1);
        qq2  += __shfl_xor(qq2, 1);
        kk2  += __shfl_xor(kk2, 1);
        float denom2 = sqrtf(qq2) * sqrtf(kk2) + 1e-8f;
        float sim2 = dot2 / denom2;
        float s2 = sim2 + __shfl_xor(sim2, 2);
        s2 += __shfl_xor(s2, 4);
        mean = s2 * 0.25f;
    }

    float mf = (mean > THRESH) ? 1.f : 0.f;
    float cw0 = cwts[0], cw1 = cwts[1];
    float mx = fmaxf(cw0, cw1);
    float e0 = expf(cw0 - mx), e1 = expf(cw1 - mx);
    float inv = 1.f / (e0 + e1);
    float fused = e0 * inv + (e1 * inv) * mf;
    float em = (fused > 0.5f) ? 1.f : 0.f;

    if (sub == 0) {
        maskf[e] = em;
        if (em != 0.f) {
            atomicAdd(&cnt[row], 1);
            atomicAdd(&cnt[col], 1);
        }
    }
}

// ============ exclusive scan over cnt[N] (3 kernels) ============
__global__ void scan_part(const int* __restrict__ cnt, int* __restrict__ part, int n)
{
    __shared__ int sd[256];
    int b = blockIdx.x, t = threadIdx.x;
    int base = b * 1024;
    int s = 0;
#pragma unroll
    for (int j = 0; j < 4; j++) {
        int idx = base + t + j * 256;
        if (idx < n) s += cnt[idx];
    }
    sd[t] = s; __syncthreads();
    for (int d = 128; d > 0; d >>= 1) {
        if (t < d) sd[t] += sd[t + d];
        __syncthreads();
    }
    if (t == 0) part[b] = sd[0];
}

__global__ void scan_small(int* part, int nb)
{
    __shared__ int sd[256];
    int t = threadIdx.x;
    sd[t] = (t < nb) ? part[t] : 0;
    __syncthreads();
    for (int d = 1; d < 256; d <<= 1) {
        int x = (t >= d) ? sd[t - d] : 0;
        __syncthreads();
        sd[t] += x;
        __syncthreads();
    }
    if (t < nb) part[t] = (t > 0) ? sd[t - 1] : 0;
}

__global__ void scan_final(const int* __restrict__ cnt, const int* __restrict__ part,
                           int* __restrict__ offs, int n)
{
    __shared__ int sd[256];
    int b = blockIdx.x, t = threadIdx.x;
    int base = b * 1024 + t * 4;
    int v[4]; int s = 0;
#pragma unroll
    for (int j = 0; j < 4; j++) {
        int idx = base + j;
        v[j] = (idx < n) ? cnt[idx] : 0;
        s += v[j];
    }
    sd[t] = s; __syncthreads();
    for (int d = 1; d < 256; d <<= 1) {
        int x = (t >= d) ? sd[t - d] : 0;
        __syncthreads();
        sd[t] += x;
        __syncthreads();
    }
    int prefix = part[b] + ((t > 0) ? sd[t - 1] : 0);
#pragma unroll
    for (int j = 0; j < 4; j++) {
        int idx = base + j;
        if (idx < n) offs[idx] = prefix;
        prefix += v[j];
    }
}

// ============ CSR scatter ============
__global__ void scatter_kernel(const int* __restrict__ ei, int Edir,
                               const float* __restrict__ maskf,
                               const int* __restrict__ cnt, const int* __restrict__ offs,
                               int* __restrict__ cursor,
                               int* __restrict__ cnbr, float* __restrict__ cwA, int Eund)
{
    int e = blockIdx.x * 256 + threadIdx.x;
    if (e >= Eund) return;
    if (maskf[e] == 0.f) return;
    int row = ei[e], col = ei[Edir + e];
    row = min(max(row, 0), N_NUM - 1);
    col = min(max(col, 0), N_NUM - 1);
    float w = 1.0f / sqrtf((float)cnt[row] * (float)cnt[col]);
    int p1 = offs[row] + atomicAdd(&cursor[row], 1);
    cnbr[p1] = col; cwA[p1] = w;
    int p2 = offs[col] + atomicAdd(&cursor[col], 1);
    cnbr[p2] = row; cwA[p2] = w;
}

// ============ propagation ============
template<int MODE>
__global__ __launch_bounds__(256)
void prop(const int* __restrict__ offs, const int* __restrict__ cnt,
          const int* __restrict__ cnbr, const float* __restrict__ cwA,
          const float* __restrict__ xin,
          const float* __restrict__ ue, const float* __restrict__ ie,
          const float* __restrict__ x1b, float* __restrict__ xout,
          float* __restrict__ tail)
{
    int wid = (blockIdx.x << 2) + (threadIdx.x >> 6);
    if (wid >= N_NUM) return;
    int lane = threadIdx.x & 63;
    int num = cnt[wid];
    if (MODE != 2 && num == 0) return;
    int start = (num > 0) ? offs[wid] : 0;
    float ax = 0.f, ay = 0.f;

    auto srcp = [&](int c) -> const float* {
        if (MODE == 0)
            return (c < U_NUM) ? (ue + (size_t)c * D_EMB) : (ie + (size_t)(c - U_NUM) * D_EMB);
        else
            return xin + (size_t)c * D_EMB;
    };

    int j = 0;
    for (; j + 4 <= num; j += 4) {
        int c0i = cnbr[start + j],     c1i = cnbr[start + j + 1];
        int c2i = cnbr[start + j + 2], c3i = cnbr[start + j + 3];
        float w0 = cwA[start + j],     w1 = cwA[start + j + 1];
        float w2 = cwA[start + j + 2], w3 = cwA[start + j + 3];
        float2 v0 = *(const float2*)(srcp(c0i) + lane * 2);
        float2 v1 = *(const float2*)(srcp(c1i) + lane * 2);
        float2 v2 = *(const float2*)(srcp(c2i) + lane * 2);
        float2 v3 = *(const float2*)(srcp(c3i) + lane * 2);
        ax += w0 * v0.x; ay += w0 * v0.y;
        ax += w1 * v1.x; ay += w1 * v1.y;
        ax += w2 * v2.x; ay += w2 * v2.y;
        ax += w3 * v3.x; ay += w3 * v3.y;
    }
    for (; j < num; ++j) {
        int c = cnbr[start + j]; float w = cwA[start + j];
        float2 v = *(const float2*)(srcp(c) + lane * 2);
        ax += w * v.x; ay += w * v.y;
    }

    size_t o = (size_t)wid * D_EMB + lane * 2;
    if (MODE == 2) {
        const float* x0p = (wid < U_NUM) ? (ue + (size_t)wid * D_EMB)
                                         : (ie + (size_t)(wid - U_NUM) * D_EMB);
        float2 x0v = *(const float2*)(x0p + lane * 2);
        *(float2*)(tail + o) = x0v;                     // embed copy (output tail)
        float ox, oy;
        if (num == 0) {
            ox = x0v.x * 0.25f; oy = x0v.y * 0.25f;
        } else {
            float2 x1v = *(const float2*)(x1b + o);
            float2 x2v = *(const float2*)(xin + o);
            ox = ((x0v.x + x1v.x) + x2v.x + ax) * 0.25f;
            oy = ((x0v.y + x1v.y) + x2v.y + ay) * 0.25f;
        }
        *(float2*)(xout + o) = make_float2(ox, oy);
    } else {
        *(float2*)(xout + o) = make_float2(ax, ay);
    }
}

// ============ launcher ============
extern "C" void kernel_launch(void* const* d_in, const int* in_sizes, int n_in,
                              void* d_out, int out_size, void* d_ws, size_t ws_size,
                              hipStream_t stream)
{
    const float* user_feat  = (const float*)d_in[0];
    const float* food_feat  = (const float*)d_in[1];
    const int*   ei         = (const int*)d_in[2];
    const float* W_user     = (const float*)d_in[3];
    const float* b_user     = (const float*)d_in[4];
    const float* W_food     = (const float*)d_in[5];
    const float* b_food     = (const float*)d_in[6];
    const float* Wq         = (const float*)d_in[7];
    const float* Wk         = (const float*)d_in[8];
    const float* cwts       = (const float*)d_in[9];
    const float* user_embed = (const float*)d_in[10];
    const float* item_embed = (const float*)d_in[11];

    const int Edir = in_sizes[2] / 2;   // 1.2M directed edges
    const int Eund = Edir / 2;          // 600K undirected ([u,f] || [f,u])

    char* ws = (char*)d_ws;
    size_t off = 0;
    auto alloc = [&](size_t nb) { size_t o = off; off += (nb + 255) & ~(size_t)255; return o; };

    float* Q     = (float*)(ws + alloc((size_t)N_NUM * D_EMB * 4));  // f32 Q|K -> xA
    float* xB    = (float*)(ws + alloc((size_t)N_NUM * D_EMB * 4));  // Eh|El planes, later prop scratch
    unsigned short* QKh = (unsigned short*)(ws + alloc((size_t)N_NUM * D_EMB * 2));
    float* maskf = (float*)(ws + alloc((size_t)Eund * 4));
    int*   cnt   = (int*)  (ws + alloc((size_t)N_NUM * 4));
    int*   offs  = (int*)  (ws + alloc((size_t)N_NUM * 4));
    int*   cursor= (int*)  (ws + alloc((size_t)N_NUM * 4));
    int*   cnbr  = (int*)  (ws + alloc((size_t)Edir * 4));
    float* cwA   = (float*)(ws + alloc((size_t)Edir * 4));
    int*   part  = (int*)  (ws + alloc((size_t)256 * 4));
    unsigned short* Wsp = (unsigned short*)(ws + alloc((size_t)196608 * 2));
    (void)ws_size; (void)n_in; (void)out_size;

    float* xA = Q;                              // N x 128, reuses Q|K after the edge stage
    unsigned short* Ehl = (unsigned short*)xB;  // 2 fp16 planes, dead before prop<0>

    // 1) pre-split weights + zero counters
    presplit_zero<<<384, 256, 0, stream>>>(W_user, W_food, Wq, Wk, Wsp, cnt, cursor);

    // 2) two GEMMs: v7 LDS-dbuf structure + upfront operand loads
    const int nbU2 = 2 * ((U_NUM + 127) / 128);   // 782
    const int nbF2 = 2 * ((F_NUM + 127) / 128);   // 314
    gemm1<<<nbU2 + nbF2, 256, 0, stream>>>(user_feat, food_feat, Wsp, b_user, b_food,
                                           Ehl, nbU2);
    gemm2<<<nbU2 + nbF2, 256, 0, stream>>>(Ehl, Wsp, Q, QKh, nbU2);

    // 3) per-edge mask + degree counts (fp16 gather, f32 borderline recheck)
    edge_kernel<<<(Eund * 8 + 255) / 256, 256, 0, stream>>>(ei, Edir, QKh, Q, cwts,
                                                            maskf, cnt, Eund);

    // 4) exclusive scan of cnt -> offs
    int nb = (N_NUM + 1023) / 1024;
    scan_part <<<nb, 256, 0, stream>>>(cnt, part, N_NUM);
    scan_small<<<1, 256, 0, stream>>>(part, nb);
    scan_final<<<nb, 256, 0, stream>>>(cnt, part, offs, N_NUM);

    // 5) CSR scatter
    scatter_kernel<<<(Eund + 255) / 256, 256, 0, stream>>>(ei, Edir, maskf, cnt, offs,
                                                           cursor, cnbr, cwA, Eund);

    // 6) three LightGCN layers; last fuses epilogue + embeds tail copy
    int pb = (N_NUM + 3) / 4;
    float* tail = (float*)d_out + (size_t)N_NUM * D_EMB;
    prop<0><<<pb, 256, 0, stream>>>(offs, cnt, cnbr, cwA, nullptr, user_embed, item_embed,
                                    nullptr, xB, nullptr);
    prop<1><<<pb, 256, 0, stream>>>(offs, cnt, cnbr, cwA, xB, user_embed, item_embed,
                                    nullptr, xA, nullptr);
    prop<2><<<pb, 256, 0, stream>>>(offs, cnt, cnbr, cwA, xA, user_embed, item_embed,
                                    xB, (float*)d_out, tail);
}

// Round 13
// 166.132 us; speedup vs baseline: 1.4816x; 1.0015x over previous
//
#include <hip/hip_runtime.h>
#include <cstdint>

#define U_NUM 50000
#define F_NUM 20000
#define N_NUM 70000
#define D_EMB 128
#define THRESH 0.3f

typedef _Float16 half8 __attribute__((ext_vector_type(8)));
typedef float f32x4 __attribute__((ext_vector_type(4)));
typedef unsigned short u16x8 __attribute__((ext_vector_type(8)));

#define NRT_U ((U_NUM + 127) / 128)   // 391 row tiles (users)
#define NRT_F ((F_NUM + 127) / 128)   // 157 row tiles (foods)
#define GRID_U (((NRT_U + 7) / 8) * 16)   // 784
#define GRID_F (((NRT_F + 7) / 8) * 16)   // 320

// paired block map: 16 consecutive bids = 8 rowTiles x 2 colHalves; the two
// halves of a rowTile are bids (base+o) and (base+o+8) -> same XCD under the
// %8 round-robin dispatch, so the second half hits A in that XCD's L2.
__device__ __forceinline__ void map_tile(int lb, int nRT, int& rt, int& ch, bool& valid)
{
    int g = lb >> 4, o = lb & 15;
    ch = (o >> 3) & 1;
    rt = g * 8 + (o & 7);
    valid = (rt < nRT);
}

// ============ pre-split weights (2 fp16 planes, transposed [n][k]) + zero counters ============
__global__ void presplit_zero(const float* __restrict__ Wu, const float* __restrict__ Wf,
                              const float* __restrict__ Wq, const float* __restrict__ Wk,
                              unsigned short* __restrict__ dst,
                              int* __restrict__ cnt, int* __restrict__ cursor)
{
    int i = blockIdx.x * 256 + threadIdx.x;
    if (i < N_NUM) { cnt[i] = 0; cursor[i] = 0; }
    if (i >= 98304) return;
    float a; size_t d; int pstride;
    if (i < 32768) {
        int n = i >> 8, k = i & 255;
        a = Wu[k * 128 + n]; d = (size_t)n * 256 + k; pstride = 32768;
    } else if (i < 65536) {
        int j = i - 32768; int n = j >> 8, k = j & 255;
        a = Wf[k * 128 + n]; d = 65536 + (size_t)n * 256 + k; pstride = 32768;
    } else if (i < 81920) {
        int j = i - 65536; int n = j >> 7, k = j & 127;
        a = Wq[k * 128 + n]; d = 131072 + (size_t)n * 128 + k; pstride = 16384;
    } else {
        int j = i - 81920; int n = j >> 7, k = j & 127;
        a = Wk[k * 128 + n]; d = 163840 + (size_t)n * 128 + k; pstride = 16384;
    }
    _Float16 c1 = (_Float16)a;            // RNE
    float r = a - (float)c1;
    _Float16 c2 = (_Float16)r;            // RNE
    dst[d]           = __builtin_bit_cast(unsigned short, c1);
    dst[d + pstride] = __builtin_bit_cast(unsigned short, c2);
}

// ============ split 8 f32 -> hi/lo fp16 fragments (RNE scalar casts) ============
__device__ __forceinline__ void split2v(const f32x4 x0, const f32x4 x1,
                                        half8& h, half8& lo)
{
    float v[8] = {x0[0], x0[1], x0[2], x0[3], x1[0], x1[1], x1[2], x1[3]};
#pragma unroll
    for (int i = 0; i < 8; i++) {
        _Float16 c1 = (_Float16)v[i];
        h[i] = c1;
        lo[i] = (_Float16)(v[i] - (float)c1);
    }
}

// ============ GEMM 1: E = relu(feat @ W1 + b1) -> fp16 hi/lo planes ============
// 128r x 64c block, 4 waves x 32 rows. W tile one-shot in LDS (72 KB, pitch-36
// rows -> conflict-free b128 reads). All A chunks upfront in regs. ONE barrier;
// k-loop is LDS+MFMA only with dependency waitcnts.
__global__ __launch_bounds__(256, 2)
void gemm1(const float* __restrict__ uf, const float* __restrict__ ff,
           const unsigned short* __restrict__ Wsp,
           const float* __restrict__ bu, const float* __restrict__ bfo,
           unsigned short* __restrict__ Eh)
{
    __shared__ unsigned short Ws[2][8][64][36];   // 73728 B

    unsigned short* El = Eh + (size_t)N_NUM * 128;
    const int bid = blockIdx.x;
    const bool isU = bid < GRID_U;
    const int lb = isU ? bid : bid - GRID_U;
    int rt, ch; bool valid;
    map_tile(lb, isU ? NRT_U : NRT_F, rt, ch, valid);
    if (!valid) return;                         // block-uniform, before barrier
    const int n0 = ch * 64;
    const int Mloc = isU ? U_NUM : F_NUM;
    const int combBase = isU ? 0 : U_NUM;
    const float* A  = isU ? uf : ff;
    const float* b1 = isU ? bu : bfo;
    const unsigned short* W = Wsp + (isU ? 0 : 65536);

    const int tid = threadIdx.x;

    // ---- one-shot W stage: 2 planes x (8kc x 64n) rows of 64 B ----
    {
        const int p = tid >> 7, rest = tid & 127;
#pragma unroll
        for (int j = 0; j < 4; ++j) {
            int row = j * 128 + rest;           // 0..511
            int kc = row >> 6, n = row & 63;
            const unsigned short* src = W + (size_t)p * 32768 + (size_t)(n0 + n) * 256 + kc * 32;
            unsigned short* d = &Ws[p][kc][n][0];
            ((uint4*)d)[0] = ((const uint4*)src)[0];
            ((uint4*)d)[1] = ((const uint4*)src)[1];
            ((uint4*)d)[2] = ((const uint4*)src)[2];
            ((uint4*)d)[3] = ((const uint4*)src)[3];
        }
    }

    const int w  = tid >> 6;
    const int l  = tid & 63;
    const int lm = l & 15;
    const int lq = l >> 4;
    const int wr = w * 32;

    const float* arow[2];
#pragma unroll
    for (int rb = 0; rb < 2; ++rb) {
        int r = min(rt * 128 + wr + rb * 16 + lm, Mloc - 1);
        arow[rb] = A + (size_t)r * 256 + lq * 8;
    }

    // ---- all A chunks upfront (2rb x 8kc x 32B/lane) ----
    f32x4 a0[2][8], a1r[2][8];
#pragma unroll
    for (int rb = 0; rb < 2; ++rb)
#pragma unroll
        for (int kc = 0; kc < 8; ++kc) {
            const f32x4* p4 = (const f32x4*)(arow[rb] + kc * 32);
            a0[rb][kc] = p4[0]; a1r[rb][kc] = p4[1];
        }

    __syncthreads();   // the only barrier

    f32x4 acc[2][4];
#pragma unroll
    for (int i = 0; i < 2; i++)
#pragma unroll
        for (int j = 0; j < 4; j++) acc[i][j] = (f32x4)0.f;

#pragma unroll
    for (int kc = 0; kc < 8; ++kc) {
        half8 ah[2], al[2];
#pragma unroll
        for (int rb = 0; rb < 2; ++rb) split2v(a0[rb][kc], a1r[rb][kc], ah[rb], al[rb]);
#pragma unroll
        for (int cb = 0; cb < 4; ++cb) {
            half8 bh = *(const half8*)&Ws[0][kc][cb * 16 + lm][lq * 8];
            half8 bl = *(const half8*)&Ws[1][kc][cb * 16 + lm][lq * 8];
#pragma unroll
            for (int rb = 0; rb < 2; ++rb) {
                acc[rb][cb] = __builtin_amdgcn_mfma_f32_16x16x32_f16(al[rb], bh, acc[rb][cb], 0, 0, 0);
                acc[rb][cb] = __builtin_amdgcn_mfma_f32_16x16x32_f16(ah[rb], bl, acc[rb][cb], 0, 0, 0);
                acc[rb][cb] = __builtin_amdgcn_mfma_f32_16x16x32_f16(ah[rb], bh, acc[rb][cb], 0, 0, 0);
            }
        }
    }

    // ---- epilogue: e = relu(acc + b); store fp16 hi/lo planes (== split2(e)) ----
#pragma unroll
    for (int cb = 0; cb < 4; ++cb) {
        const int col = n0 + cb * 16 + lm;
        const float bb = b1[col];
#pragma unroll
        for (int rb = 0; rb < 2; ++rb)
#pragma unroll
            for (int rg = 0; rg < 4; ++rg) {
                int lr = wr + rb * 16 + lq * 4 + rg;
                if (rt * 128 + lr < Mloc) {
                    size_t rr = (size_t)(combBase + rt * 128 + lr);
                    float e = fmaxf(acc[rb][cb][rg] + bb, 0.f);
                    _Float16 c1 = (_Float16)e;
                    _Float16 c2 = (_Float16)(e - (float)c1);
                    Eh[rr * 128 + col] = __builtin_bit_cast(unsigned short, c1);
                    El[rr * 128 + col] = __builtin_bit_cast(unsigned short, c2);
                }
            }
    }
}

// ============ GEMM 2: QK = E @ W2 (f32 + fp16 copy); same barrier-free structure ============
__global__ __launch_bounds__(256, 3)
void gemm2(const unsigned short* __restrict__ Eh,
           const unsigned short* __restrict__ Wsp,
           float* __restrict__ Qo, unsigned short* __restrict__ QKh)
{
    __shared__ unsigned short Ws[2][4][64][36];   // 36864 B

    const unsigned short* El = Eh + (size_t)N_NUM * 128;
    const int bid = blockIdx.x;
    const bool isU = bid < GRID_U;
    const int lb = isU ? bid : bid - GRID_U;
    int rt, ch; bool valid;
    map_tile(lb, isU ? NRT_U : NRT_F, rt, ch, valid);
    if (!valid) return;
    const int n0 = ch * 64;
    const int Mloc = isU ? U_NUM : F_NUM;
    const int combBase = isU ? 0 : U_NUM;
    const unsigned short* W = Wsp + (isU ? 131072 : 163840);

    const int tid = threadIdx.x;

    // ---- one-shot W stage: 2 planes x (4kc x 64n) rows of 64 B ----
    {
        const int p = tid >> 7, rest = tid & 127;
#pragma unroll
        for (int j = 0; j < 2; ++j) {
            int row = j * 128 + rest;           // 0..255
            int kc = row >> 6, n = row & 63;
            const unsigned short* src = W + (size_t)p * 16384 + (size_t)(n0 + n) * 128 + kc * 32;
            unsigned short* d = &Ws[p][kc][n][0];
            ((uint4*)d)[0] = ((const uint4*)src)[0];
            ((uint4*)d)[1] = ((const uint4*)src)[1];
            ((uint4*)d)[2] = ((const uint4*)src)[2];
            ((uint4*)d)[3] = ((const uint4*)src)[3];
        }
    }

    const int w  = tid >> 6;
    const int l  = tid & 63;
    const int lm = l & 15;
    const int lq = l >> 4;
    const int wr = w * 32;

    size_t erow[2];
#pragma unroll
    for (int rb = 0; rb < 2; ++rb) {
        int r = min(rt * 128 + wr + rb * 16 + lm, Mloc - 1) + combBase;
        erow[rb] = (size_t)r * 128 + lq * 8;
    }

    // ---- all E chunks upfront (hi+lo planes, 64 VGPR) ----
    u16x8 ph[2][4], pl[2][4];
#pragma unroll
    for (int rb = 0; rb < 2; ++rb)
#pragma unroll
        for (int kc = 0; kc < 4; ++kc) {
            ph[rb][kc] = *(const u16x8*)(Eh + erow[rb] + kc * 32);
            pl[rb][kc] = *(const u16x8*)(El + erow[rb] + kc * 32);
        }

    __syncthreads();   // the only barrier

    f32x4 acc[2][4];
#pragma unroll
    for (int i = 0; i < 2; i++)
#pragma unroll
        for (int j = 0; j < 4; j++) acc[i][j] = (f32x4)0.f;

#pragma unroll
    for (int kc = 0; kc < 4; ++kc) {
#pragma unroll
        for (int cb = 0; cb < 4; ++cb) {
            half8 bh = *(const half8*)&Ws[0][kc][cb * 16 + lm][lq * 8];
            half8 bl = *(const half8*)&Ws[1][kc][cb * 16 + lm][lq * 8];
#pragma unroll
            for (int rb = 0; rb < 2; ++rb) {
                half8 ah = __builtin_bit_cast(half8, ph[rb][kc]);
                half8 al = __builtin_bit_cast(half8, pl[rb][kc]);
                acc[rb][cb] = __builtin_amdgcn_mfma_f32_16x16x32_f16(al, bh, acc[rb][cb], 0, 0, 0);
                acc[rb][cb] = __builtin_amdgcn_mfma_f32_16x16x32_f16(ah, bl, acc[rb][cb], 0, 0, 0);
                acc[rb][cb] = __builtin_amdgcn_mfma_f32_16x16x32_f16(ah, bh, acc[rb][cb], 0, 0, 0);
            }
        }
    }

#pragma unroll
    for (int cb = 0; cb < 4; ++cb) {
        const int col = n0 + cb * 16 + lm;
#pragma unroll
        for (int rb = 0; rb < 2; ++rb)
#pragma unroll
            for (int rg = 0; rg < 4; ++rg) {
                int lr = wr + rb * 16 + lq * 4 + rg;
                if (rt * 128 + lr < Mloc) {
                    size_t rr = (size_t)(combBase + rt * 128 + lr);
                    float v = acc[rb][cb][rg];
                    Qo[rr * 128 + col] = v;
                    QKh[rr * 128 + col] = __builtin_bit_cast(unsigned short, (_Float16)v);
                }
            }
    }
}

// ============ per-edge multi-head cosine mask: fp16 gather + f32 borderline recheck ============
__global__ __launch_bounds__(256)
void edge_kernel(const int* __restrict__ ei, int Edir,
                 const unsigned short* __restrict__ QKh, const float* __restrict__ QKf,
                 const float* __restrict__ cwts,
                 float* __restrict__ maskf, int* __restrict__ cnt, int Eund)
{
    int gid = blockIdx.x * 256 + threadIdx.x;
    int e = gid >> 3;
    if (e >= Eund) return;
    int sub = gid & 7;
    int row = ei[e];
    int col = ei[Edir + e];
    row = min(max(row, 0), N_NUM - 1);
    col = min(max(col, 0), N_NUM - 1);
    int u  = (row < U_NUM) ? row : col;
    int fg = (row < U_NUM) ? col : row;
    u = min(max(u, 0), U_NUM - 1);
    int f = min(max(fg - U_NUM, 0), F_NUM - 1);
    const size_t qrow = (size_t)u * D_EMB;
    const size_t krow = (size_t)(U_NUM + f) * D_EMB;

    const unsigned short* qh = QKh + qrow + sub * 16;
    const unsigned short* kh = QKh + krow + sub * 16;
    u16x8 qa = *(const u16x8*)(qh);
    u16x8 qb = *(const u16x8*)(qh + 8);
    u16x8 ka = *(const u16x8*)(kh);
    u16x8 kb = *(const u16x8*)(kh + 8);
    float dot = 0.f, qq = 0.f, kk = 0.f;
#pragma unroll
    for (int i = 0; i < 8; i++) {
        float qv = (float)__builtin_bit_cast(_Float16, (unsigned short)qa[i]);
        float kv = (float)__builtin_bit_cast(_Float16, (unsigned short)ka[i]);
        dot += qv * kv; qq += qv * qv; kk += kv * kv;
    }
#pragma unroll
    for (int i = 0; i < 8; i++) {
        float qv = (float)__builtin_bit_cast(_Float16, (unsigned short)qb[i]);
        float kv = (float)__builtin_bit_cast(_Float16, (unsigned short)kb[i]);
        dot += qv * kv; qq += qv * qv; kk += kv * kv;
    }
    dot += __shfl_xor(dot, 1);
    qq  += __shfl_xor(qq, 1);
    kk  += __shfl_xor(kk, 1);
    float denom = sqrtf(qq) * sqrtf(kk) + 1e-8f;
    float sim = dot / denom;
    float s = sim + __shfl_xor(sim, 2);
    s += __shfl_xor(s, 4);
    float mean = s * 0.25f;

    if (fabsf(mean - THRESH) < 0.03f) {
        const float4* qp = (const float4*)(QKf + qrow + sub * 16);
        const float4* kp = (const float4*)(QKf + krow + sub * 16);
        float dot2 = 0.f, qq2 = 0.f, kk2 = 0.f;
#pragma unroll
        for (int i = 0; i < 4; i++) {
            float4 a = qp[i]; float4 b = kp[i];
            dot2 += a.x * b.x + a.y * b.y + a.z * b.z + a.w * b.w;
            qq2  += a.x * a.x + a.y * a.y + a.z * a.z + a.w * a.w;
            kk2  += b.x * b.x + b.y * b.y + b.z * b.z + b.w * b.w;
        }
        dot2 += __shfl_xor(dot2, 1);
        qq2  += __shfl_xor(qq2, 1);
        kk2  += __shfl_xor(kk2, 1);
        float denom2 = sqrtf(qq2) * sqrtf(kk2) + 1e-8f;
        float sim2 = dot2 / denom2;
        float s2 = sim2 + __shfl_xor(sim2, 2);
        s2 += __shfl_xor(s2, 4);
        mean = s2 * 0.25f;
    }

    float mf = (mean > THRESH) ? 1.f : 0.f;
    float cw0 = cwts[0], cw1 = cwts[1];
    float mx = fmaxf(cw0, cw1);
    float e0 = expf(cw0 - mx), e1 = expf(cw1 - mx);
    float inv = 1.f / (e0 + e1);
    float fused = e0 * inv + (e1 * inv) * mf;
    float em = (fused > 0.5f) ? 1.f : 0.f;

    if (sub == 0) {
        maskf[e] = em;
        if (em != 0.f) {
            atomicAdd(&cnt[row], 1);
            atomicAdd(&cnt[col], 1);
        }
    }
}

// ============ exclusive scan over cnt[N] (3 kernels) ============
__global__ void scan_part(const int* __restrict__ cnt, int* __restrict__ part, int n)
{
    __shared__ int sd[256];
    int b = blockIdx.x, t = threadIdx.x;
    int base = b * 1024;
    int s = 0;
#pragma unroll
    for (int j = 0; j < 4; j++) {
        int idx = base + t + j * 256;
        if (idx < n) s += cnt[idx];
    }
    sd[t] = s; __syncthreads();
    for (int d = 128; d > 0; d >>= 1) {
        if (t < d) sd[t] += sd[t + d];
        __syncthreads();
    }
    if (t == 0) part[b] = sd[0];
}

__global__ void scan_small(int* part, int nb)
{
    __shared__ int sd[256];
    int t = threadIdx.x;
    sd[t] = (t < nb) ? part[t] : 0;
    __syncthreads();
    for (int d = 1; d < 256; d <<= 1) {
        int x = (t >= d) ? sd[t - d] : 0;
        __syncthreads();
        sd[t] += x;
        __syncthreads();
    }
    if (t < nb) part[t] = (t > 0) ? sd[t - 1] : 0;
}

__global__ void scan_final(const int* __restrict__ cnt, const int* __restrict__ part,
                           int* __restrict__ offs, int n)
{
    __shared__ int sd[256];
    int b = blockIdx.x, t = threadIdx.x;
    int base = b * 1024 + t * 4;
    int v[4]; int s = 0;
#pragma unroll
    for (int j = 0; j < 4; j++) {
        int idx = base + j;
        v[j] = (idx < n) ? cnt[idx] : 0;
        s += v[j];
    }
    sd[t] = s; __syncthreads();
    for (int d = 1; d < 256; d <<= 1) {
        int x = (t >= d) ? sd[t - d] : 0;
        __syncthreads();
        sd[t] += x;
        __syncthreads();
    }
    int prefix = part[b] + ((t > 0) ? sd[t - 1] : 0);
#pragma unroll
    for (int j = 0; j < 4; j++) {
        int idx = base + j;
        if (idx < n) offs[idx] = prefix;
        prefix += v[j];
    }
}

// ============ CSR scatter ============
__global__ void scatter_kernel(const int* __restrict__ ei, int Edir,
                               const float* __restrict__ maskf,
                               const int* __restrict__ cnt, const int* __restrict__ offs,
                               int* __restrict__ cursor,
                               int* __restrict__ cnbr, float* __restrict__ cwA, int Eund)
{
    int e = blockIdx.x * 256 + threadIdx.x;
    if (e >= Eund) return;
    if (maskf[e] == 0.f) return;
    int row = ei[e], col = ei[Edir + e];
    row = min(max(row, 0), N_NUM - 1);
    col = min(max(col, 0), N_NUM - 1);
    float w = 1.0f / sqrtf((float)cnt[row] * (float)cnt[col]);
    int p1 = offs[row] + atomicAdd(&cursor[row], 1);
    cnbr[p1] = col; cwA[p1] = w;
    int p2 = offs[col] + atomicAdd(&cursor[col], 1);
    cnbr[p2] = row; cwA[p2] = w;
}

// ============ propagation ============
template<int MODE>
__global__ __launch_bounds__(256)
void prop(const int* __restrict__ offs, const int* __restrict__ cnt,
          const int* __restrict__ cnbr, const float* __restrict__ cwA,
          const float* __restrict__ xin,
          const float* __restrict__ ue, const float* __restrict__ ie,
          const float* __restrict__ x1b, float* __restrict__ xout,
          float* __restrict__ tail)
{
    int wid = (blockIdx.x << 2) + (threadIdx.x >> 6);
    if (wid >= N_NUM) return;
    int lane = threadIdx.x & 63;
    int num = cnt[wid];
    if (MODE != 2 && num == 0) return;
    int start = (num > 0) ? offs[wid] : 0;
    float ax = 0.f, ay = 0.f;

    auto srcp = [&](int c) -> const float* {
        if (MODE == 0)
            return (c < U_NUM) ? (ue + (size_t)c * D_EMB) : (ie + (size_t)(c - U_NUM) * D_EMB);
        else
            return xin + (size_t)c * D_EMB;
    };

    int j = 0;
    for (; j + 4 <= num; j += 4) {
        int c0i = cnbr[start + j],     c1i = cnbr[start + j + 1];
        int c2i = cnbr[start + j + 2], c3i = cnbr[start + j + 3];
        float w0 = cwA[start + j],     w1 = cwA[start + j + 1];
        float w2 = cwA[start + j + 2], w3 = cwA[start + j + 3];
        float2 v0 = *(const float2*)(srcp(c0i) + lane * 2);
        float2 v1 = *(const float2*)(srcp(c1i) + lane * 2);
        float2 v2 = *(const float2*)(srcp(c2i) + lane * 2);
        float2 v3 = *(const float2*)(srcp(c3i) + lane * 2);
        ax += w0 * v0.x; ay += w0 * v0.y;
        ax += w1 * v1.x; ay += w1 * v1.y;
        ax += w2 * v2.x; ay += w2 * v2.y;
        ax += w3 * v3.x; ay += w3 * v3.y;
    }
    for (; j < num; ++j) {
        int c = cnbr[start + j]; float w = cwA[start + j];
        float2 v = *(const float2*)(srcp(c) + lane * 2);
        ax += w * v.x; ay += w * v.y;
    }

    size_t o = (size_t)wid * D_EMB + lane * 2;
    if (MODE == 2) {
        const float* x0p = (wid < U_NUM) ? (ue + (size_t)wid * D_EMB)
                                         : (ie + (size_t)(wid - U_NUM) * D_EMB);
        float2 x0v = *(const float2*)(x0p + lane * 2);
        *(float2*)(tail + o) = x0v;                     // embed copy (output tail)
        float ox, oy;
        if (num == 0) {
            ox = x0v.x * 0.25f; oy = x0v.y * 0.25f;
        } else {
            float2 x1v = *(const float2*)(x1b + o);
            float2 x2v = *(const float2*)(xin + o);
            ox = ((x0v.x + x1v.x) + x2v.x + ax) * 0.25f;
            oy = ((x0v.y + x1v.y) + x2v.y + ay) * 0.25f;
        }
        *(float2*)(xout + o) = make_float2(ox, oy);
    } else {
        *(float2*)(xout + o) = make_float2(ax, ay);
    }
}

// ============ launcher ============
extern "C" void kernel_launch(void* const* d_in, const int* in_sizes, int n_in,
                              void* d_out, int out_size, void* d_ws, size_t ws_size,
                              hipStream_t stream)
{
    const float* user_feat  = (const float*)d_in[0];
    const float* food_feat  = (const float*)d_in[1];
    const int*   ei         = (const int*)d_in[2];
    const float* W_user     = (const float*)d_in[3];
    const float* b_user     = (const float*)d_in[4];
    const float* W_food     = (const float*)d_in[5];
    const float* b_food     = (const float*)d_in[6];
    const float* Wq         = (const float*)d_in[7];
    const float* Wk         = (const float*)d_in[8];
    const float* cwts       = (const float*)d_in[9];
    const float* user_embed = (const float*)d_in[10];
    const float* item_embed = (const float*)d_in[11];

    const int Edir = in_sizes[2] / 2;   // 1.2M directed edges
    const int Eund = Edir / 2;          // 600K undirected ([u,f] || [f,u])

    char* ws = (char*)d_ws;
    size_t off = 0;
    auto alloc = [&](size_t nb) { size_t o = off; off += (nb + 255) & ~(size_t)255; return o; };

    float* Q     = (float*)(ws + alloc((size_t)N_NUM * D_EMB * 4));  // f32 Q|K -> xA
    float* xB    = (float*)(ws + alloc((size_t)N_NUM * D_EMB * 4));  // Eh|El planes, later prop scratch
    unsigned short* QKh = (unsigned short*)(ws + alloc((size_t)N_NUM * D_EMB * 2));
    float* maskf = (float*)(ws + alloc((size_t)Eund * 4));
    int*   cnt   = (int*)  (ws + alloc((size_t)N_NUM * 4));
    int*   offs  = (int*)  (ws + alloc((size_t)N_NUM * 4));
    int*   cursor= (int*)  (ws + alloc((size_t)N_NUM * 4));
    int*   cnbr  = (int*)  (ws + alloc((size_t)Edir * 4));
    float* cwA   = (float*)(ws + alloc((size_t)Edir * 4));
    int*   part  = (int*)  (ws + alloc((size_t)256 * 4));
    unsigned short* Wsp = (unsigned short*)(ws + alloc((size_t)196608 * 2));
    (void)ws_size; (void)n_in; (void)out_size;

    float* xA = Q;                              // N x 128, reuses Q|K after the edge stage
    unsigned short* Ehl = (unsigned short*)xB;  // 2 fp16 planes, dead before prop<0>

    // 1) pre-split weights + zero counters
    presplit_zero<<<384, 256, 0, stream>>>(W_user, W_food, Wq, Wk, Wsp, cnt, cursor);

    // 2) two GEMMs: one-shot LDS W, barrier-free k-loop, XCD-paired col-split
    gemm1<<<GRID_U + GRID_F, 256, 0, stream>>>(user_feat, food_feat, Wsp,
                                               b_user, b_food, Ehl);
    gemm2<<<GRID_U + GRID_F, 256, 0, stream>>>(Ehl, Wsp, Q, QKh);

    // 3) per-edge mask + degree counts (fp16 gather, f32 borderline recheck)
    edge_kernel<<<(Eund * 8 + 255) / 256, 256, 0, stream>>>(ei, Edir, QKh, Q, cwts,
                                                            maskf, cnt, Eund);

    // 4) exclusive scan of cnt -> offs
    int nb = (N_NUM + 1023) / 1024;
    scan_part <<<nb, 256, 0, stream>>>(cnt, part, N_NUM);
    scan_small<<<1, 256, 0, stream>>>(part, nb);
    scan_final<<<nb, 256, 0, stream>>>(cnt, part, offs, N_NUM);

    // 5) CSR scatter
    scatter_kernel<<<(Eund + 255) / 256, 256, 0, stream>>>(ei, Edir, maskf, cnt, offs,
                                                           cursor, cnbr, cwA, Eund);

    // 6) three LightGCN layers; last fuses epilogue + embeds tail copy
    int pb = (N_NUM + 3) / 4;
    float* tail = (float*)d_out + (size_t)N_NUM * D_EMB;
    prop<0><<<pb, 256, 0, stream>>>(offs, cnt, cnbr, cwA, nullptr, user_embed, item_embed,
                                    nullptr, xB, nullptr);
    prop<1><<<pb, 256, 0, stream>>>(offs, cnt, cnbr, cwA, xB, user_embed, item_embed,
                                    nullptr, xA, nullptr);
    prop<2><<<pb, 256, 0, stream>>>(offs, cnt, cnbr, cwA, xA, user_embed, item_embed,
                                    xB, (float*)d_out, tail);
}

// Round 14
// 150.092 us; speedup vs baseline: 1.6399x; 1.1069x over previous
//
#include <hip/hip_runtime.h>
#include <cstdint>

#define U_NUM 50000
#define F_NUM 20000
#define N_NUM 70000
#define D_EMB 128
#define THRESH 0.3f

typedef _Float16 half8 __attribute__((ext_vector_type(8)));
typedef float f32x4 __attribute__((ext_vector_type(4)));
typedef unsigned short u16x8 __attribute__((ext_vector_type(8)));

#define NRT_U ((U_NUM + 127) / 128)       // 391 row tiles (users)
#define NRT_F ((F_NUM + 127) / 128)       // 157 row tiles (foods)
#define GRID_U (((NRT_U + 7) / 8) * 16)   // 784
#define GRID_F (((NRT_F + 7) / 8) * 16)   // 320

// paired block map: 16 consecutive bids = 8 rowTiles x 2 colHalves; halves of a
// rowTile are bids (base+o)/(base+o+8) -> same XCD under %8 round-robin, so the
// second half hits A in that XCD's L2 (verified R13: FETCH 71.7->37.3 MB).
__device__ __forceinline__ void map_tile(int lb, int nRT, int& rt, int& ch, bool& valid)
{
    int g = lb >> 4, o = lb & 15;
    ch = (o >> 3) & 1;
    rt = g * 8 + (o & 7);
    valid = (rt < nRT);
}

// async 16B global -> LDS (wave-uniform LDS base + lane*16; per-lane global src)
__device__ __forceinline__ void gl_lds16(const void* g, void* l)
{
    __builtin_amdgcn_global_load_lds(
        (const __attribute__((address_space(1))) unsigned int*)g,
        (__attribute__((address_space(3))) unsigned int*)l, 16, 0, 0);
}

// ============ pre-split weights (2 fp16 planes, transposed [n][k]) + zero counters ============
__global__ void presplit_zero(const float* __restrict__ Wu, const float* __restrict__ Wf,
                              const float* __restrict__ Wq, const float* __restrict__ Wk,
                              unsigned short* __restrict__ dst,
                              int* __restrict__ cnt, int* __restrict__ cursor)
{
    int i = blockIdx.x * 256 + threadIdx.x;
    if (i < N_NUM) { cnt[i] = 0; cursor[i] = 0; }
    if (i >= 98304) return;
    float a; size_t d; int pstride;
    if (i < 32768) {
        int n = i >> 8, k = i & 255;
        a = Wu[k * 128 + n]; d = (size_t)n * 256 + k; pstride = 32768;
    } else if (i < 65536) {
        int j = i - 32768; int n = j >> 8, k = j & 255;
        a = Wf[k * 128 + n]; d = 65536 + (size_t)n * 256 + k; pstride = 32768;
    } else if (i < 81920) {
        int j = i - 65536; int n = j >> 7, k = j & 127;
        a = Wq[k * 128 + n]; d = 131072 + (size_t)n * 128 + k; pstride = 16384;
    } else {
        int j = i - 81920; int n = j >> 7, k = j & 127;
        a = Wk[k * 128 + n]; d = 163840 + (size_t)n * 128 + k; pstride = 16384;
    }
    _Float16 c1 = (_Float16)a;            // RNE
    float r = a - (float)c1;
    _Float16 c2 = (_Float16)r;            // RNE
    dst[d]           = __builtin_bit_cast(unsigned short, c1);
    dst[d + pstride] = __builtin_bit_cast(unsigned short, c2);
}

// ============ split 8 f32 -> hi/lo fp16 fragments (RNE scalar casts) ============
__device__ __forceinline__ void split2v(const f32x4 x0, const f32x4 x1,
                                        half8& h, half8& lo)
{
    float v[8] = {x0[0], x0[1], x0[2], x0[3], x1[0], x1[1], x1[2], x1[3]};
#pragma unroll
    for (int i = 0; i < 8; i++) {
        _Float16 c1 = (_Float16)v[i];
        h[i] = c1;
        lo[i] = (_Float16)(v[i] - (float)c1);
    }
}

// ============ GEMM 1: E = relu(feat @ W1 + b1) -> fp16 hi/lo planes ============
// m97 pattern: global_load_lds async staging (A-tile 16KB + W-tile 8KB per kc,
// double-buffered, 48KB LDS, 3 blocks/CU). One barrier per kc; its vmcnt drain
// overlaps the compute phase. XOR-swizzled on both sides (linear DMA dest).
__global__ __launch_bounds__(256, 3)
void gemm1(const float* __restrict__ uf, const float* __restrict__ ff,
           const unsigned short* __restrict__ Wsp,
           const float* __restrict__ bu, const float* __restrict__ bfo,
           unsigned short* __restrict__ Eh)
{
    __shared__ char lds[49152];   // A: [0,32768) bufs of 16384; W: [32768,49152) bufs of 8192

    unsigned short* El = Eh + (size_t)N_NUM * 128;
    const int bid = blockIdx.x;
    const bool isU = bid < GRID_U;
    const int lb = isU ? bid : bid - GRID_U;
    int rt, chf; bool valid;
    map_tile(lb, isU ? NRT_U : NRT_F, rt, chf, valid);
    if (!valid) return;
    const int n0 = chf * 64;
    const int Mloc = isU ? U_NUM : F_NUM;
    const int combBase = isU ? 0 : U_NUM;
    const float* A  = isU ? uf : ff;
    const float* b1 = isU ? bu : bfo;
    const unsigned short* W = Wsp + (isU ? 0 : 65536);

    const int tid = threadIdx.x;
    const int w  = tid >> 6;
    const int l  = tid & 63;
    const int lm = l & 15;
    const int lq = l >> 4;
    const int wr = w * 32;

    auto stage = [&](int b, int kc) {
        // A tile: 128 rows x 32 k f32 (row = 128 B = 8 chunks), chunk ^= row&7
#pragma unroll
        for (int j = 0; j < 4; ++j) {
            int off = w * 4096 + j * 1024 + l * 16;
            int row = off >> 7;
            int ch  = (off & 127) >> 4;
            int gch = ch ^ (row & 7);
            int gr  = min(rt * 128 + row, Mloc - 1);
            const float* src = A + (size_t)gr * 256 + kc * 32 + gch * 4;
            gl_lds16(src, lds + b * 16384 + w * 4096 + j * 1024);
        }
        // W tile: 2 planes x 64 n x 32 k fp16 (row = 64 B = 4 chunks), chunk ^= (n>>1)&3
#pragma unroll
        for (int j = 0; j < 2; ++j) {
            int off = w * 2048 + j * 1024 + l * 16;
            int p   = off >> 12;
            int n   = (off & 4095) >> 6;
            int ch  = (off & 63) >> 4;
            int gch = ch ^ ((n >> 1) & 3);
            const unsigned short* src = W + (size_t)p * 32768 + (size_t)(n0 + n) * 256 + kc * 32 + gch * 8;
            gl_lds16(src, lds + 32768 + b * 8192 + w * 2048 + j * 1024);
        }
    };

    stage(0, 0);
    __syncthreads();

    f32x4 acc[2][4];
#pragma unroll
    for (int i = 0; i < 2; i++)
#pragma unroll
        for (int j = 0; j < 4; j++) acc[i][j] = (f32x4)0.f;

    int buf = 0;
#pragma unroll
    for (int kc = 0; kc < 8; ++kc) {
        if (kc < 7) stage(buf ^ 1, kc + 1);   // async; drains at the barrier below

        half8 ah[2], al[2];
#pragma unroll
        for (int rb = 0; rb < 2; ++rb) {
            int lr = wr + rb * 16 + lm;
            int r7 = lr & 7;
            const float* basep = (const float*)(lds + buf * 16384 + lr * 128);
            f32x4 x0 = *(const f32x4*)(basep + ((((lq * 2)     ) ^ r7) << 2));
            f32x4 x1 = *(const f32x4*)(basep + ((((lq * 2) + 1) ^ r7) << 2));
            split2v(x0, x1, ah[rb], al[rb]);
        }
#pragma unroll
        for (int cb = 0; cb < 4; ++cb) {
            int n = cb * 16 + lm;
            int wc = lq ^ ((n >> 1) & 3);
            const char* wbase = lds + 32768 + buf * 8192;
            half8 bh = *(const half8*)(wbase + n * 64 + wc * 16);
            half8 bl = *(const half8*)(wbase + 4096 + n * 64 + wc * 16);
#pragma unroll
            for (int rb = 0; rb < 2; ++rb) {
                acc[rb][cb] = __builtin_amdgcn_mfma_f32_16x16x32_f16(al[rb], bh, acc[rb][cb], 0, 0, 0);
                acc[rb][cb] = __builtin_amdgcn_mfma_f32_16x16x32_f16(ah[rb], bl, acc[rb][cb], 0, 0, 0);
                acc[rb][cb] = __builtin_amdgcn_mfma_f32_16x16x32_f16(ah[rb], bh, acc[rb][cb], 0, 0, 0);
            }
        }
        __syncthreads();
        buf ^= 1;
    }

    // ---- epilogue: e = relu(acc + b); store fp16 hi/lo planes (== split2(e)) ----
#pragma unroll
    for (int cb = 0; cb < 4; ++cb) {
        const int col = n0 + cb * 16 + lm;
        const float bb = b1[col];
#pragma unroll
        for (int rb = 0; rb < 2; ++rb)
#pragma unroll
            for (int rg = 0; rg < 4; ++rg) {
                int lr = wr + rb * 16 + lq * 4 + rg;
                if (rt * 128 + lr < Mloc) {
                    size_t rr = (size_t)(combBase + rt * 128 + lr);
                    float e = fmaxf(acc[rb][cb][rg] + bb, 0.f);
                    _Float16 c1 = (_Float16)e;
                    _Float16 c2 = (_Float16)(e - (float)c1);
                    Eh[rr * 128 + col] = __builtin_bit_cast(unsigned short, c1);
                    El[rr * 128 + col] = __builtin_bit_cast(unsigned short, c2);
                }
            }
    }
}

// ============ GEMM 2: QK = E @ W2 (f32 + fp16 copy); same m97 structure ============
__global__ __launch_bounds__(256, 3)
void gemm2(const unsigned short* __restrict__ Eh,
           const unsigned short* __restrict__ Wsp,
           float* __restrict__ Qo, unsigned short* __restrict__ QKh)
{
    __shared__ char lds[49152];   // E: [0,32768) bufs of 16384; W: [32768,49152) bufs of 8192

    const unsigned short* El = Eh + (size_t)N_NUM * 128;
    const int bid = blockIdx.x;
    const bool isU = bid < GRID_U;
    const int lb = isU ? bid : bid - GRID_U;
    int rt, chf; bool valid;
    map_tile(lb, isU ? NRT_U : NRT_F, rt, chf, valid);
    if (!valid) return;
    const int n0 = chf * 64;
    const int Mloc = isU ? U_NUM : F_NUM;
    const int combBase = isU ? 0 : U_NUM;
    const unsigned short* W = Wsp + (isU ? 131072 : 163840);

    const int tid = threadIdx.x;
    const int w  = tid >> 6;
    const int l  = tid & 63;
    const int lm = l & 15;
    const int lq = l >> 4;
    const int wr = w * 32;

    auto stage = [&](int b, int kc) {
        // E tile: 2 planes x 128 rows x 32 k fp16 (row = 64 B), chunk ^= (row>>1)&3
#pragma unroll
        for (int j = 0; j < 4; ++j) {
            int off = w * 4096 + j * 1024 + l * 16;
            int p   = off >> 13;
            int ro  = (off & 8191) >> 6;
            int ch  = (off & 63) >> 4;
            int gch = ch ^ ((ro >> 1) & 3);
            int gr  = min(rt * 128 + ro, Mloc - 1) + combBase;
            const unsigned short* src = (p ? El : Eh) + (size_t)gr * 128 + kc * 32 + gch * 8;
            gl_lds16(src, lds + b * 16384 + w * 4096 + j * 1024);
        }
        // W tile: 2 planes x 64 n x 32 k fp16, chunk ^= (n>>1)&3
#pragma unroll
        for (int j = 0; j < 2; ++j) {
            int off = w * 2048 + j * 1024 + l * 16;
            int p   = off >> 12;
            int n   = (off & 4095) >> 6;
            int ch  = (off & 63) >> 4;
            int gch = ch ^ ((n >> 1) & 3);
            const unsigned short* src = W + (size_t)p * 16384 + (size_t)(n0 + n) * 128 + kc * 32 + gch * 8;
            gl_lds16(src, lds + 32768 + b * 8192 + w * 2048 + j * 1024);
        }
    };

    stage(0, 0);
    __syncthreads();

    f32x4 acc[2][4];
#pragma unroll
    for (int i = 0; i < 2; i++)
#pragma unroll
        for (int j = 0; j < 4; j++) acc[i][j] = (f32x4)0.f;

    int buf = 0;
#pragma unroll
    for (int kc = 0; kc < 4; ++kc) {
        if (kc < 3) stage(buf ^ 1, kc + 1);

        half8 ah[2], al[2];
#pragma unroll
        for (int rb = 0; rb < 2; ++rb) {
            int lr = wr + rb * 16 + lm;
            int ech = lq ^ ((lr >> 1) & 3);
            const char* eb = lds + buf * 16384;
            ah[rb] = *(const half8*)(eb + lr * 64 + ech * 16);
            al[rb] = *(const half8*)(eb + 8192 + lr * 64 + ech * 16);
        }
#pragma unroll
        for (int cb = 0; cb < 4; ++cb) {
            int n = cb * 16 + lm;
            int wc = lq ^ ((n >> 1) & 3);
            const char* wbase = lds + 32768 + buf * 8192;
            half8 bh = *(const half8*)(wbase + n * 64 + wc * 16);
            half8 bl = *(const half8*)(wbase + 4096 + n * 64 + wc * 16);
#pragma unroll
            for (int rb = 0; rb < 2; ++rb) {
                acc[rb][cb] = __builtin_amdgcn_mfma_f32_16x16x32_f16(al[rb], bh, acc[rb][cb], 0, 0, 0);
                acc[rb][cb] = __builtin_amdgcn_mfma_f32_16x16x32_f16(ah[rb], bl, acc[rb][cb], 0, 0, 0);
                acc[rb][cb] = __builtin_amdgcn_mfma_f32_16x16x32_f16(ah[rb], bh, acc[rb][cb], 0, 0, 0);
            }
        }
        __syncthreads();
        buf ^= 1;
    }

#pragma unroll
    for (int cb = 0; cb < 4; ++cb) {
        const int col = n0 + cb * 16 + lm;
#pragma unroll
        for (int rb = 0; rb < 2; ++rb)
#pragma unroll
            for (int rg = 0; rg < 4; ++rg) {
                int lr = wr + rb * 16 + lq * 4 + rg;
                if (rt * 128 + lr < Mloc) {
                    size_t rr = (size_t)(combBase + rt * 128 + lr);
                    float v = acc[rb][cb][rg];
                    Qo[rr * 128 + col] = v;
                    QKh[rr * 128 + col] = __builtin_bit_cast(unsigned short, (_Float16)v);
                }
            }
    }
}

// ============ per-edge multi-head cosine mask: fp16 gather + f32 borderline recheck ============
__global__ __launch_bounds__(256)
void edge_kernel(const int* __restrict__ ei, int Edir,
                 const unsigned short* __restrict__ QKh, const float* __restrict__ QKf,
                 const float* __restrict__ cwts,
                 float* __restrict__ maskf, int* __restrict__ cnt, int Eund)
{
    int gid = blockIdx.x * 256 + threadIdx.x;
    int e = gid >> 3;
    if (e >= Eund) return;
    int sub = gid & 7;
    int row = ei[e];
    int col = ei[Edir + e];
    row = min(max(row, 0), N_NUM - 1);
    col = min(max(col, 0), N_NUM - 1);
    int u  = (row < U_NUM) ? row : col;
    int fg = (row < U_NUM) ? col : row;
    u = min(max(u, 0), U_NUM - 1);
    int f = min(max(fg - U_NUM, 0), F_NUM - 1);
    const size_t qrow = (size_t)u * D_EMB;
    const size_t krow = (size_t)(U_NUM + f) * D_EMB;

    const unsigned short* qh = QKh + qrow + sub * 16;
    const unsigned short* kh = QKh + krow + sub * 16;
    u16x8 qa = *(const u16x8*)(qh);
    u16x8 qb = *(const u16x8*)(qh + 8);
    u16x8 ka = *(const u16x8*)(kh);
    u16x8 kb = *(const u16x8*)(kh + 8);
    float dot = 0.f, qq = 0.f, kk = 0.f;
#pragma unroll
    for (int i = 0; i < 8; i++) {
        float qv = (float)__builtin_bit_cast(_Float16, (unsigned short)qa[i]);
        float kv = (float)__builtin_bit_cast(_Float16, (unsigned short)ka[i]);
        dot += qv * kv; qq += qv * qv; kk += kv * kv;
    }
#pragma unroll
    for (int i = 0; i < 8; i++) {
        float qv = (float)__builtin_bit_cast(_Float16, (unsigned short)qb[i]);
        float kv = (float)__builtin_bit_cast(_Float16, (unsigned short)kb[i]);
        dot += qv * kv; qq += qv * qv; kk += kv * kv;
    }
    dot += __shfl_xor(dot, 1);
    qq  += __shfl_xor(qq, 1);
    kk  += __shfl_xor(kk, 1);
    float denom = sqrtf(qq) * sqrtf(kk) + 1e-8f;
    float sim = dot / denom;
    float s = sim + __shfl_xor(sim, 2);
    s += __shfl_xor(s, 4);
    float mean = s * 0.25f;

    if (fabsf(mean - THRESH) < 0.03f) {
        const float4* qp = (const float4*)(QKf + qrow + sub * 16);
        const float4* kp = (const float4*)(QKf + krow + sub * 16);
        float dot2 = 0.f, qq2 = 0.f, kk2 = 0.f;
#pragma unroll
        for (int i = 0; i < 4; i++) {
            float4 a = qp[i]; float4 b = kp[i];
            dot2 += a.x * b.x + a.y * b.y + a.z * b.z + a.w * b.w;
            qq2  += a.x * a.x + a.y * a.y + a.z * a.z + a.w * a.w;
            kk2  += b.x * b.x + b.y * b.y + b.z * b.z + b.w * b.w;
        }
        dot2 += __shfl_xor(dot2, 1);
        qq2  += __shfl_xor(qq2, 1);
        kk2  += __shfl_xor(kk2, 1);
        float denom2 = sqrtf(qq2) * sqrtf(kk2) + 1e-8f;
        float sim2 = dot2 / denom2;
        float s2 = sim2 + __shfl_xor(sim2, 2);
        s2 += __shfl_xor(s2, 4);
        mean = s2 * 0.25f;
    }

    float mf = (mean > THRESH) ? 1.f : 0.f;
    float cw0 = cwts[0], cw1 = cwts[1];
    float mx = fmaxf(cw0, cw1);
    float e0 = expf(cw0 - mx), e1 = expf(cw1 - mx);
    float inv = 1.f / (e0 + e1);
    float fused = e0 * inv + (e1 * inv) * mf;
    float em = (fused > 0.5f) ? 1.f : 0.f;

    if (sub == 0) {
        maskf[e] = em;
        if (em != 0.f) {
            atomicAdd(&cnt[row], 1);
            atomicAdd(&cnt[col], 1);
        }
    }
}

// ============ exclusive scan over cnt[N] (3 kernels) ============
__global__ void scan_part(const int* __restrict__ cnt, int* __restrict__ part, int n)
{
    __shared__ int sd[256];
    int b = blockIdx.x, t = threadIdx.x;
    int base = b * 1024;
    int s = 0;
#pragma unroll
    for (int j = 0; j < 4; j++) {
        int idx = base + t + j * 256;
        if (idx < n) s += cnt[idx];
    }
    sd[t] = s; __syncthreads();
    for (int d = 128; d > 0; d >>= 1) {
        if (t < d) sd[t] += sd[t + d];
        __syncthreads();
    }
    if (t == 0) part[b] = sd[0];
}

__global__ void scan_small(int* part, int nb)
{
    __shared__ int sd[256];
    int t = threadIdx.x;
    sd[t] = (t < nb) ? part[t] : 0;
    __syncthreads();
    for (int d = 1; d < 256; d <<= 1) {
        int x = (t >= d) ? sd[t - d] : 0;
        __syncthreads();
        sd[t] += x;
        __syncthreads();
    }
    if (t < nb) part[t] = (t > 0) ? sd[t - 1] : 0;
}

__global__ void scan_final(const int* __restrict__ cnt, const int* __restrict__ part,
                           int* __restrict__ offs, int n)
{
    __shared__ int sd[256];
    int b = blockIdx.x, t = threadIdx.x;
    int base = b * 1024 + t * 4;
    int v[4]; int s = 0;
#pragma unroll
    for (int j = 0; j < 4; j++) {
        int idx = base + j;
        v[j] = (idx < n) ? cnt[idx] : 0;
        s += v[j];
    }
    sd[t] = s; __syncthreads();
    for (int d = 1; d < 256; d <<= 1) {
        int x = (t >= d) ? sd[t - d] : 0;
        __syncthreads();
        sd[t] += x;
        __syncthreads();
    }
    int prefix = part[b] + ((t > 0) ? sd[t - 1] : 0);
#pragma unroll
    for (int j = 0; j < 4; j++) {
        int idx = base + j;
        if (idx < n) offs[idx] = prefix;
        prefix += v[j];
    }
}

// ============ CSR scatter ============
__global__ void scatter_kernel(const int* __restrict__ ei, int Edir,
                               const float* __restrict__ maskf,
                               const int* __restrict__ cnt, const int* __restrict__ offs,
                               int* __restrict__ cursor,
                               int* __restrict__ cnbr, float* __restrict__ cwA, int Eund)
{
    int e = blockIdx.x * 256 + threadIdx.x;
    if (e >= Eund) return;
    if (maskf[e] == 0.f) return;
    int row = ei[e], col = ei[Edir + e];
    row = min(max(row, 0), N_NUM - 1);
    col = min(max(col, 0), N_NUM - 1);
    float w = 1.0f / sqrtf((float)cnt[row] * (float)cnt[col]);
    int p1 = offs[row] + atomicAdd(&cursor[row], 1);
    cnbr[p1] = col; cwA[p1] = w;
    int p2 = offs[col] + atomicAdd(&cursor[col], 1);
    cnbr[p2] = row; cwA[p2] = w;
}

// ============ propagation ============
template<int MODE>
__global__ __launch_bounds__(256)
void prop(const int* __restrict__ offs, const int* __restrict__ cnt,
          const int* __restrict__ cnbr, const float* __restrict__ cwA,
          const float* __restrict__ xin,
          const float* __restrict__ ue, const float* __restrict__ ie,
          const float* __restrict__ x1b, float* __restrict__ xout,
          float* __restrict__ tail)
{
    int wid = (blockIdx.x << 2) + (threadIdx.x >> 6);
    if (wid >= N_NUM) return;
    int lane = threadIdx.x & 63;
    int num = cnt[wid];
    if (MODE != 2 && num == 0) return;
    int start = (num > 0) ? offs[wid] : 0;
    float ax = 0.f, ay = 0.f;

    auto srcp = [&](int c) -> const float* {
        if (MODE == 0)
            return (c < U_NUM) ? (ue + (size_t)c * D_EMB) : (ie + (size_t)(c - U_NUM) * D_EMB);
        else
            return xin + (size_t)c * D_EMB;
    };

    int j = 0;
    for (; j + 4 <= num; j += 4) {
        int c0i = cnbr[start + j],     c1i = cnbr[start + j + 1];
        int c2i = cnbr[start + j + 2], c3i = cnbr[start + j + 3];
        float w0 = cwA[start + j],     w1 = cwA[start + j + 1];
        float w2 = cwA[start + j + 2], w3 = cwA[start + j + 3];
        float2 v0 = *(const float2*)(srcp(c0i) + lane * 2);
        float2 v1 = *(const float2*)(srcp(c1i) + lane * 2);
        float2 v2 = *(const float2*)(srcp(c2i) + lane * 2);
        float2 v3 = *(const float2*)(srcp(c3i) + lane * 2);
        ax += w0 * v0.x; ay += w0 * v0.y;
        ax += w1 * v1.x; ay += w1 * v1.y;
        ax += w2 * v2.x; ay += w2 * v2.y;
        ax += w3 * v3.x; ay += w3 * v3.y;
    }
    for (; j < num; ++j) {
        int c = cnbr[start + j]; float w = cwA[start + j];
        float2 v = *(const float2*)(srcp(c) + lane * 2);
        ax += w * v.x; ay += w * v.y;
    }

    size_t o = (size_t)wid * D_EMB + lane * 2;
    if (MODE == 2) {
        const float* x0p = (wid < U_NUM) ? (ue + (size_t)wid * D_EMB)
                                         : (ie + (size_t)(wid - U_NUM) * D_EMB);
        float2 x0v = *(const float2*)(x0p + lane * 2);
        *(float2*)(tail + o) = x0v;                     // embed copy (output tail)
        float ox, oy;
        if (num == 0) {
            ox = x0v.x * 0.25f; oy = x0v.y * 0.25f;
        } else {
            float2 x1v = *(const float2*)(x1b + o);
            float2 x2v = *(const float2*)(xin + o);
            ox = ((x0v.x + x1v.x) + x2v.x + ax) * 0.25f;
            oy = ((x0v.y + x1v.y) + x2v.y + ay) * 0.25f;
        }
        *(float2*)(xout + o) = make_float2(ox, oy);
    } else {
        *(float2*)(xout + o) = make_float2(ax, ay);
    }
}

// ============ launcher ============
extern "C" void kernel_launch(void* const* d_in, const int* in_sizes, int n_in,
                              void* d_out, int out_size, void* d_ws, size_t ws_size,
                              hipStream_t stream)
{
    const float* user_feat  = (const float*)d_in[0];
    const float* food_feat  = (const float*)d_in[1];
    const int*   ei         = (const int*)d_in[2];
    const float* W_user     = (const float*)d_in[3];
    const float* b_user     = (const float*)d_in[4];
    const float* W_food     = (const float*)d_in[5];
    const float* b_food     = (const float*)d_in[6];
    const float* Wq         = (const float*)d_in[7];
    const float* Wk         = (const float*)d_in[8];
    const float* cwts       = (const float*)d_in[9];
    const float* user_embed = (const float*)d_in[10];
    const float* item_embed = (const float*)d_in[11];

    const int Edir = in_sizes[2] / 2;   // 1.2M directed edges
    const int Eund = Edir / 2;          // 600K undirected ([u,f] || [f,u])

    char* ws = (char*)d_ws;
    size_t off = 0;
    auto alloc = [&](size_t nb) { size_t o = off; off += (nb + 255) & ~(size_t)255; return o; };

    float* Q     = (float*)(ws + alloc((size_t)N_NUM * D_EMB * 4));  // f32 Q|K -> xA
    float* xB    = (float*)(ws + alloc((size_t)N_NUM * D_EMB * 4));  // Eh|El planes, later prop scratch
    unsigned short* QKh = (unsigned short*)(ws + alloc((size_t)N_NUM * D_EMB * 2));
    float* maskf = (float*)(ws + alloc((size_t)Eund * 4));
    int*   cnt   = (int*)  (ws + alloc((size_t)N_NUM * 4));
    int*   offs  = (int*)  (ws + alloc((size_t)N_NUM * 4));
    int*   cursor= (int*)  (ws + alloc((size_t)N_NUM * 4));
    int*   cnbr  = (int*)  (ws + alloc((size_t)Edir * 4));
    float* cwA   = (float*)(ws + alloc((size_t)Edir * 4));
    int*   part  = (int*)  (ws + alloc((size_t)256 * 4));
    unsigned short* Wsp = (unsigned short*)(ws + alloc((size_t)196608 * 2));
    (void)ws_size; (void)n_in; (void)out_size;

    float* xA = Q;                              // N x 128, reuses Q|K after the edge stage
    unsigned short* Ehl = (unsigned short*)xB;  // 2 fp16 planes, dead before prop<0>

    // 1) pre-split weights + zero counters
    presplit_zero<<<384, 256, 0, stream>>>(W_user, W_food, Wq, Wk, Wsp, cnt, cursor);

    // 2) two GEMMs: m97 global_load_lds dbuf staging, XCD-paired col-split
    gemm1<<<GRID_U + GRID_F, 256, 0, stream>>>(user_feat, food_feat, Wsp,
                                               b_user, b_food, Ehl);
    gemm2<<<GRID_U + GRID_F, 256, 0, stream>>>(Ehl, Wsp, Q, QKh);

    // 3) per-edge mask + degree counts (fp16 gather, f32 borderline recheck)
    edge_kernel<<<(Eund * 8 + 255) / 256, 256, 0, stream>>>(ei, Edir, QKh, Q, cwts,
                                                            maskf, cnt, Eund);

    // 4) exclusive scan of cnt -> offs
    int nb = (N_NUM + 1023) / 1024;
    scan_part <<<nb, 256, 0, stream>>>(cnt, part, N_NUM);
    scan_small<<<1, 256, 0, stream>>>(part, nb);
    scan_final<<<nb, 256, 0, stream>>>(cnt, part, offs, N_NUM);

    // 5) CSR scatter
    scatter_kernel<<<(Eund + 255) / 256, 256, 0, stream>>>(ei, Edir, maskf, cnt, offs,
                                                           cursor, cnbr, cwA, Eund);

    // 6) three LightGCN layers; last fuses epilogue + embeds tail copy
    int pb = (N_NUM + 3) / 4;
    float* tail = (float*)d_out + (size_t)N_NUM * D_EMB;
    prop<0><<<pb, 256, 0, stream>>>(offs, cnt, cnbr, cwA, nullptr, user_embed, item_embed,
                                    nullptr, xB, nullptr);
    prop<1><<<pb, 256, 0, stream>>>(offs, cnt, cnbr, cwA, xB, user_embed, item_embed,
                                    nullptr, xA, nullptr);
    prop<2><<<pb, 256, 0, stream>>>(offs, cnt, cnbr, cwA, xA, user_embed, item_embed,
                                    xB, (float*)d_out, tail);
}